// Round 10
// baseline (972.245 us; speedup 1.0000x reference)
//
#include <hip/hip_runtime.h>
#include <stdint.h>

typedef unsigned short u16;
typedef __attribute__((ext_vector_type(8))) short sx8;   // 8 bf16 (4 VGPRs) — MFMA A/B frag
typedef __attribute__((ext_vector_type(4))) float fx4;   // MFMA C/D frag

__device__ __forceinline__ float bf2f(u16 u) {
    union { unsigned i; float f; } v; v.i = ((unsigned)u) << 16; return v.f;
}
__device__ __forceinline__ u16 f2bf(float f) {
    union { float f; unsigned i; } v; v.f = f;
    return (u16)((v.i + 0x7FFFu + ((v.i >> 16) & 1u)) >> 16);
}
#define MFMA(a, b, c) __builtin_amdgcn_mfma_f32_16x16x32_bf16((a), (b), (c), 0, 0, 0)

#define GLDS(gp, lp) \
    __builtin_amdgcn_global_load_lds((const __attribute__((address_space(1))) void*)(gp), \
                                     (__attribute__((address_space(3))) void*)(lp), 16, 0, 0)

// 0.125 (1/sqrt(64)) * log2(e): attention scale folded with the exp->exp2
// domain change. Softmax keeps max-subtraction (sum >= 1, NaN-proof);
// 2^(S'-mx)/sum equals natural-exp softmax exactly (base change cancels).
#define QSCALE 0.18033688011112042f
// masked score -1e-12 nats -> log2 domain
#define MASKC (-1.442695e-12f)

// ---------- m97-style MFMA GEMM: C[M,N] = A[M,K] @ BT[N,K]^T, all bf16 ----------
// R10: reverted to the R8-proven BK=32 form (R9's BK=64 regressed: barrier
// events halved but drain cost scales with outstanding loads — net negative).
// scaleZ0: when set, `scale` applies only to batch z==0 (folds the attention
// scale into the Q projection of the fused QKV GEMM).
template<int BN>
__global__ __launch_bounds__(256) void gemm_bt(
    const u16* __restrict__ A, long sA, int ldA,
    const u16* __restrict__ BT, long sBT, int ldBT,
    u16* __restrict__ C, long sC, int ldC,
    int K,
    const u16* __restrict__ bias, int bz,
    const void* __restrict__ resid, int residF32, long rofs,
    float scale, int scaleZ0, int relu)
{
    constexpr int BK = 32;
    constexpr int TM = 4;
    constexpr int TN = BN / 32;
    constexpr int AI = 2;
    constexpr int BI = BN / 64;

    __shared__ __align__(16) u16 As[128 * BK];
    __shared__ __align__(16) u16 Bs[BN * BK];

    const int tid  = threadIdx.x;
    const int w    = tid >> 6;
    const int lane = tid & 63;
    const int quad = lane >> 4;
    const int n16  = lane & 15;
    const int wrow = w >> 1, wcol = w & 1;

    // XCD-chunked swizzle over the (x,y) plane (bijective when nxy%8==0)
    int bx = blockIdx.x, by = blockIdx.y;
    {
        int nxy = gridDim.x * gridDim.y;
        if ((nxy & 7) == 0) {
            int bid = by * gridDim.x + bx;
            int wgs = (bid & 7) * (nxy >> 3) + (bid >> 3);
            bx = wgs % gridDim.x;
            by = wgs / gridDim.x;
        }
    }
    const int m0 = by * 128, n0 = bx * BN;
    const long z = blockIdx.z;
    const float es = (z == 0 || !scaleZ0) ? scale : 1.f;
    A  += z * sA;
    BT += z * sBT;
    C  += z * sC;

    fx4 acc[TM][TN] = {};

    for (int k0 = 0; k0 < K; k0 += BK) {
        #pragma unroll
        for (int i = 0; i < AI; ++i) {
            unsigned base = (unsigned)(w * AI + i) * 1024u;
            unsigned off  = base + (unsigned)lane * 16u;
            unsigned row  = off >> 6;
            unsigned col  = (off & 63u) >> 1;
            GLDS(A + (long)(m0 + row) * ldA + k0 + col, (char*)As + base);
        }
        #pragma unroll
        for (int i = 0; i < BI; ++i) {
            unsigned base = (unsigned)(w * BI + i) * 1024u;
            unsigned off  = base + (unsigned)lane * 16u;
            unsigned row  = off >> 6;
            unsigned col  = (off & 63u) >> 1;
            GLDS(BT + (long)(n0 + row) * ldBT + k0 + col, (char*)Bs + base);
        }
        __syncthreads();

        sx8 af[TM], bfr[TN];
        #pragma unroll
        for (int r = 0; r < TM; ++r)
            af[r] = *(const sx8*)&As[(wrow * 64 + r * 16 + n16) * BK + quad * 8];
        #pragma unroll
        for (int c = 0; c < TN; ++c)
            bfr[c] = *(const sx8*)&Bs[(wcol * (TN * 16) + c * 16 + n16) * BK + quad * 8];
        #pragma unroll
        for (int r = 0; r < TM; ++r)
            #pragma unroll
            for (int c = 0; c < TN; ++c)
                acc[r][c] = MFMA(af[r], bfr[c], acc[r][c]);
        __syncthreads();
    }

    #pragma unroll
    for (int r = 0; r < TM; ++r) {
        int row = m0 + wrow * 64 + r * 16 + quad * 4;
        #pragma unroll
        for (int c = 0; c < TN; ++c) {
            int col = n0 + wcol * (TN * 16) + c * 16 + n16;
            float bv = bias ? bf2f(bias[bz * (int)z + col]) : 0.f;
            #pragma unroll
            for (int g = 0; g < 4; ++g) {
                long idx = (long)(row + g) * ldC + col;
                float xv = acc[r][c][g] * es + bv;
                if (resid)
                    xv += residF32 ? ((const float*)resid)[rofs + idx]
                                   : bf2f(((const u16*)resid)[rofs + idx]);
                if (relu) xv = fmaxf(xv, 0.f);
                C[idx] = f2bf(xv);
            }
        }
    }
}

// ---------- fused attention: S'=(Q*QSCALE)@Kt, head-softmax (exp2+max), O=PV ----------
// R10 = R8 (proven 925us best) + ONE change: block-rotated m-chunk order.
// Mechanism: all resident blocks launch simultaneously, have identical
// per-iteration timing, and barriers re-align their waves -> the 4 blocks/CU
// sit in the SAME phase (MFMA burst / VALU softmax / barrier drain) at the
// same time, so co-residency never fills stalls (counters: 46% occupancy yet
// MfmaUtil 4.6 + VALU 21.5 = CU ~75% idle). The m-chunk loop is commutative
// (head-softmax per-chunk independent, PV sum over m commutes), so each block
// starts at rotation (wg&7): consecutive wgs within an XCD get different
// phases -> one block's MFMA overlaps another's softmax/drain.
// Frozen R8 internals: exp2+max-sub softmax, f2bf S-store (MFMA->asm hazard
// avoidance), cvt_pk P-store on plain-VALU inputs, rcpf, mask prefetch,
// XCD-chunked swizzle, 2-way m-split + add_bf reduction.
// qb [b][16h][1024 l][64 d]; kt [(b,h)][m][d] reshape-view K_t; vt [b][16h][64 d][1024 m].
__global__ __launch_bounds__(256, 4) void attn_fused(
    const u16* __restrict__ qb, const u16* __restrict__ kt,
    const u16* __restrict__ vt, const int* __restrict__ mask,
    u16* __restrict__ p0, u16* __restrict__ p1)
{
    constexpr int MC = 64;           // m-chunk
    constexpr int LM = MC + 8;       // 72 (pad; rows stay 16B-aligned: 144B stride)
    constexpr int SH = 16 * LM;      // per-head stride = 1152 u16
    __shared__ __align__(16) u16 Ss[16 * SH];   // 36,864 B

    const int tid = threadIdx.x, w = tid >> 6, lane = tid & 63;
    const int quad = lane >> 4, n16 = lane & 15;

    // XCD-chunked swizzle (1024 blocks, 8 XCDs, bijective)
    const int wg = ((blockIdx.x & 7) << 7) + (blockIdx.x >> 3);
    const int l0 = (wg & 63) * 16;
    const long bo = (long)((wg >> 6) & 7) * 1048576;
    const int zz = wg >> 9;
    const int mbase = zz * 512;
    const int rot = wg & 7;          // per-block phase rotation
    u16* __restrict__ po = zz ? p1 : p0;

    // softmax work split: thread covers (l, m-pair) p = tid + 256*j
    const int sl0 = tid >> 5,         smp0 = (tid & 31) * 2;
    const int sl1 = (tid + 256) >> 5, smp1 = ((tid + 256) & 31) * 2;

    // resident Q B-frags for this wave's 4 heads (col=l, k=d); Q pre-scaled
    sx8 qf[4][2];
    #pragma unroll
    for (int i = 0; i < 4; ++i) {
        const u16* qp = qb + bo + (w * 4 + i) * 65536 + (l0 + n16) * 64 + quad * 8;
        qf[i][0] = *(const sx8*)qp;
        qf[i][1] = *(const sx8*)(qp + 32);
    }

    fx4 of[4][4] = {};   // partial-O accumulators [head][d-tile]

    for (int it = 0; it < 8; ++it) {
        const int mt = (it + rot) & 7;     // rotated, commutative chunk order
        const int m0 = mbase + mt * MC;
        // ---- mask prefetch (plain loads; complete by the QK->softmax barrier) ----
        const int2 mk0 = *(const int2*)&mask[bo + (long)(l0 + sl0) * 1024 + m0 + smp0];
        const int2 mk1 = *(const int2*)&mask[bo + (long)(l0 + sl1) * 1024 + m0 + smp1];
        // ---- S'^T = K @ Qs^T : A-frag rows = m (from kt), B-frag cols = l ----
        #pragma unroll
        for (int i = 0; i < 4; ++i) {
            const int h = w * 4 + i;
            const u16* kp = kt + bo + h * 65536 + (long)m0 * 64;
            #pragma unroll
            for (int nt = 0; nt < 4; ++nt) {
                const u16* kr = kp + (nt * 16 + n16) * 64 + quad * 8;
                fx4 s = {};
                s = MFMA(*(const sx8*)kr,        qf[i][0], s);
                s = MFMA(*(const sx8*)(kr + 32), qf[i][1], s);
                // D: row = m = quad*4 + reg (consecutive), col = l = n16
                // f2bf IR path (NOT asm): compiler inserts the MFMA->VALU hazard waits
                uint2 pk;
                pk.x = (unsigned)f2bf(s[0]) | ((unsigned)f2bf(s[1]) << 16);
                pk.y = (unsigned)f2bf(s[2]) | ((unsigned)f2bf(s[3]) << 16);
                *(uint2*)&Ss[h * SH + n16 * LM + nt * 16 + quad * 4] = pk;
            }
        }
        __syncthreads();
        // ---- softmax over 16 heads, pointwise in (l,m); exp2 domain + max-sub ----
        // pair-packed: 16 l x 32 m-pairs = 512 positions, 2 per thread.
        #pragma unroll
        for (int j = 0; j < 2; ++j) {
            const int l = j ? sl1 : sl0, mp = j ? smp1 : smp0;
            const int2 mk = j ? mk1 : mk0;
            u16* col = &Ss[l * LM + mp];
            float v0[16], v1[16], mx0 = -1e30f, mx1 = -1e30f;
            #pragma unroll
            for (int h = 0; h < 16; ++h) {
                unsigned pr = *(const unsigned*)&col[h * SH];
                float a = (mk.x == 0) ? MASKC : bf2f((u16)(pr & 0xffff));
                float b = (mk.y == 0) ? MASKC : bf2f((u16)(pr >> 16));
                v0[h] = a; v1[h] = b;
                mx0 = fmaxf(mx0, a); mx1 = fmaxf(mx1, b);
            }
            float s0 = 0.f, s1 = 0.f;
            #pragma unroll
            for (int h = 0; h < 16; ++h) {
                v0[h] = exp2f(v0[h] - mx0); s0 += v0[h];
                v1[h] = exp2f(v1[h] - mx1); s1 += v1[h];
            }
            const float i0 = __builtin_amdgcn_rcpf(s0);
            const float i1 = __builtin_amdgcn_rcpf(s1);
            #pragma unroll
            for (int h = 0; h < 16; ++h) {
                // cvt_pk on plain VALU inputs — R4/R8-proven pattern
                float e0 = v0[h] * i0, e1 = v1[h] * i1;
                unsigned pk_;
                asm("v_cvt_pk_bf16_f32 %0, %1, %2" : "=v"(pk_) : "v"(e0), "v"(e1));
                *(unsigned*)&col[h * SH] = pk_;
            }
        }
        __syncthreads();
        // ---- O += P @ V (A-frag rows = l from Ss, B-frag from vt, m contiguous) ----
        #pragma unroll
        for (int i = 0; i < 4; ++i) {
            const int h = w * 4 + i;
            const u16* sp = &Ss[h * SH + n16 * LM];
            sx8 a0 = *(const sx8*)(sp + quad * 8);
            sx8 a1 = *(const sx8*)(sp + 32 + quad * 8);
            const u16* vp = vt + bo + h * 65536 + (long)n16 * 1024 + m0 + quad * 8;
            #pragma unroll
            for (int dt = 0; dt < 4; ++dt) {
                of[i][dt] = MFMA(a0, *(const sx8*)(vp + dt * 16384),      of[i][dt]);
                of[i][dt] = MFMA(a1, *(const sx8*)(vp + dt * 16384 + 32), of[i][dt]);
            }
        }
        __syncthreads();
    }

    // ---- epilogue: head-major flat store of this half's partial O ----
    #pragma unroll
    for (int i = 0; i < 4; ++i) {
        const int h = w * 4 + i;
        #pragma unroll
        for (int dt = 0; dt < 4; ++dt)
            #pragma unroll
            for (int r = 0; r < 4; ++r)
                po[bo + h * 65536 + (long)(l0 + quad * 4 + r) * 64 + dt * 16 + n16]
                    = f2bf(of[i][dt][r]);
    }
}

// ---------- bf16 partial-O reduction: b := bf16(a + b), element-wise in-place ----------
__global__ __launch_bounds__(256) void add_bf(
    const u16* __restrict__ a, u16* __restrict__ b)
{
    long i = ((long)blockIdx.x * 256 + threadIdx.x) * 8;
    uint4 x = *(const uint4*)(a + i);
    uint4 y = *(const uint4*)(b + i);
    uint4 r;
    unsigned* xp = (unsigned*)&x; unsigned* yp = (unsigned*)&y; unsigned* rp = (unsigned*)&r;
    #pragma unroll
    for (int k = 0; k < 4; ++k) {
        float lo = bf2f((u16)(xp[k] & 0xffff)) + bf2f((u16)(yp[k] & 0xffff));
        float hi = bf2f((u16)(xp[k] >> 16))    + bf2f((u16)(yp[k] >> 16));
        rp[k] = (unsigned)f2bf(lo) | ((unsigned)f2bf(hi) << 16);
    }
    *(uint4*)(b + i) = r;
}

// ---------- fp32 -> bf16 elementwise ----------
__global__ __launch_bounds__(256) void convert_f2b(
    const float* __restrict__ in, u16* __restrict__ out)
{
    long i = ((long)blockIdx.x * 256 + threadIdx.x) * 4;
    fx4 v = *(const fx4*)(in + i);
    uint2 o;
    o.x = (unsigned)f2bf(v[0]) | ((unsigned)f2bf(v[1]) << 16);
    o.y = (unsigned)f2bf(v[2]) | ((unsigned)f2bf(v[3]) << 16);
    *(uint2*)(out + i) = o;
}

// ---------- 4x fp32 [1024][1024] -> bf16 transposed, one launch (z selects src) ----------
__global__ __launch_bounds__(256) void transpose4_f2b(
    const float* a0, const float* a1, const float* a2, const float* a3,
    u16* __restrict__ out)
{
    __shared__ float t[32][33];
    const float* in = blockIdx.z == 0 ? a0 : blockIdx.z == 1 ? a1
                    : blockIdx.z == 2 ? a2 : a3;
    out += (long)blockIdx.z * 1048576;
    int c0 = blockIdx.x * 32, r0 = blockIdx.y * 32;
    int tx = threadIdx.x & 31, ty = threadIdx.x >> 5;
    #pragma unroll
    for (int i = 0; i < 4; ++i)
        t[ty + i * 8][tx] = in[(long)(r0 + ty + i * 8) * 1024 + c0 + tx];
    __syncthreads();
    #pragma unroll
    for (int i = 0; i < 4; ++i)
        out[(long)(c0 + ty + i * 8) * 1024 + r0 + tx] = f2bf(t[tx][ty + i * 8]);
}

// ---------- fp32 [R][C] -> bf16 transposed [C][R] ----------
__global__ __launch_bounds__(256) void transpose_f2b(
    const float* __restrict__ in, u16* __restrict__ out, int R, int C)
{
    __shared__ float t[32][33];
    int c0 = blockIdx.x * 32, r0 = blockIdx.y * 32;
    int tx = threadIdx.x & 31, ty = threadIdx.x >> 5;
    #pragma unroll
    for (int i = 0; i < 4; ++i)
        t[ty + i * 8][tx] = in[(long)(r0 + ty + i * 8) * C + c0 + tx];
    __syncthreads();
    #pragma unroll
    for (int i = 0; i < 4; ++i)
        out[(long)(c0 + ty + i * 8) * R + r0 + tx] = f2bf(t[tx][ty + i * 8]);
}

// ---------- bf16 batched transpose ----------
__global__ __launch_bounds__(256) void transpose_bf(
    const u16* __restrict__ in, u16* __restrict__ out, int R, int C)
{
    __shared__ u16 t[32][33];
    long zoff = (long)blockIdx.z * (long)R * (long)C;
    in += zoff; out += zoff;
    int c0 = blockIdx.x * 32, r0 = blockIdx.y * 32;
    int tx = threadIdx.x & 31, ty = threadIdx.x >> 5;
    #pragma unroll
    for (int i = 0; i < 4; ++i)
        t[ty + i * 8][tx] = in[(long)(r0 + ty + i * 8) * C + c0 + tx];
    __syncthreads();
    #pragma unroll
    for (int i = 0; i < 4; ++i)
        out[(long)(c0 + ty + i * 8) * R + r0 + tx] = t[tx][ty + i * 8];
}

// ---------- pack biases fp32 -> bf16 [bq|bk|bv|bc|b1|b2]; bq pre-scaled QSCALE ----------
__global__ __launch_bounds__(256) void pack_bias(
    const float* bq, const float* bk, const float* bv, const float* bc,
    const float* b1, const float* b2, u16* __restrict__ out)
{
    int i = blockIdx.x * 256 + threadIdx.x;
    float v;
    if      (i < 1024) v = bq[i] * QSCALE;
    else if (i < 2048) v = bk[i - 1024];
    else if (i < 3072) v = bv[i - 2048];
    else if (i < 4096) v = bc[i - 3072];
    else if (i < 8192) v = b1[i - 4096];
    else               v = b2[i - 8192];
    out[i] = f2bf(v);
}

// ---------- LayerNorm (ddof=1, /(std+eps)) ----------
__global__ __launch_bounds__(256) void layernorm_row(
    const u16* __restrict__ in, const float* __restrict__ g,
    const float* __restrict__ be, void* __restrict__ out, int outF32)
{
    int wave = threadIdx.x >> 6, lane = threadIdx.x & 63;
    long row = (long)blockIdx.x * 4 + wave;
    const u16* p = in + row * 1024 + lane * 16;

    float x[16];
    uint4 a = ((const uint4*)p)[0], b = ((const uint4*)p)[1];
    {
        unsigned u;
        u = a.x; x[0] = bf2f(u & 0xffff);  x[1] = bf2f(u >> 16);
        u = a.y; x[2] = bf2f(u & 0xffff);  x[3] = bf2f(u >> 16);
        u = a.z; x[4] = bf2f(u & 0xffff);  x[5] = bf2f(u >> 16);
        u = a.w; x[6] = bf2f(u & 0xffff);  x[7] = bf2f(u >> 16);
        u = b.x; x[8] = bf2f(u & 0xffff);  x[9] = bf2f(u >> 16);
        u = b.y; x[10] = bf2f(u & 0xffff); x[11] = bf2f(u >> 16);
        u = b.z; x[12] = bf2f(u & 0xffff); x[13] = bf2f(u >> 16);
        u = b.w; x[14] = bf2f(u & 0xffff); x[15] = bf2f(u >> 16);
    }
    float s = 0.f, ss = 0.f;
    #pragma unroll
    for (int i = 0; i < 16; ++i) { s += x[i]; ss += x[i] * x[i]; }
    #pragma unroll
    for (int o = 32; o >= 1; o >>= 1) { s += __shfl_down(s, o); ss += __shfl_down(ss, o); }
    s = __shfl(s, 0); ss = __shfl(ss, 0);
    float mean = s * (1.f / 1024.f);
    float var  = fmaxf((ss - 1024.f * mean * mean) * (1.f / 1023.f), 0.f);
    float rinv = 1.f / (sqrtf(var) + 1e-12f);

    int col = lane * 16;
    if (outF32) {
        float* ov = (float*)out + row * 1024 + col;
        #pragma unroll
        for (int i = 0; i < 16; ++i)
            ov[i] = g[col + i] * ((x[i] - mean) * rinv) + be[col + i];
    } else {
        u16* ov = (u16*)out + row * 1024 + col;
        #pragma unroll
        for (int i = 0; i < 16; ++i)
            ov[i] = f2bf(g[col + i] * ((x[i] - mean) * rinv) + be[col + i]);
    }
}

// ---------- launch ----------
// ws map (MB; peak 96 + 18KB bias):
//  [0,16)  xb -> p0 (m-half-0 partial O)
//  [16,22) wqkvT  [22,24) wcT (contiguous: one transpose4 launch)
//  [24,40) qb -> t0/x1
//  [40,56) kb -> vt (full V^T over dead kb) -> fh lower
//  [56,72) vb -> p1 (m-half-1 partial O) -> ao (after add_bf) -> fh upper
//  [72,88) kt (reshape-view K_t, all b) -> w1T/w2T post-attention
//  [88,96) pre2 (FFN phase; free during attention)
//  [96,+18KB) packed biases
extern "C" void kernel_launch(void* const* d_in, const int* in_sizes, int n_in,
                              void* d_out, int out_size, void* d_ws, size_t ws_size,
                              hipStream_t stream)
{
    const float* xf  = (const float*)d_in[0];
    const int* mask  = (const int*)d_in[1];
    const float* wq = (const float*)d_in[2];  const float* bq = (const float*)d_in[3];
    const float* wk = (const float*)d_in[4];  const float* bk = (const float*)d_in[5];
    const float* wv = (const float*)d_in[6];  const float* bv = (const float*)d_in[7];
    const float* wc = (const float*)d_in[8];  const float* bc = (const float*)d_in[9];
    const float* g1 = (const float*)d_in[10]; const float* be1 = (const float*)d_in[11];
    const float* w1 = (const float*)d_in[12]; const float* b1 = (const float*)d_in[13];
    const float* w2 = (const float*)d_in[14]; const float* b2 = (const float*)d_in[15];
    const float* g2 = (const float*)d_in[16]; const float* be2 = (const float*)d_in[17];

    char* ws = (char*)d_ws;
    const long MB = 1 << 20;
    u16* xb    = (u16*)(ws + 0 * MB);
    u16* wqkvT = (u16*)(ws + 16 * MB);
    u16* wcT   = (u16*)(ws + 22 * MB);
    u16* qb    = (u16*)(ws + 24 * MB);
    u16* kb    = (u16*)(ws + 40 * MB);
    u16* vb    = (u16*)(ws + 56 * MB);
    u16* kt    = (u16*)(ws + 72 * MB);
    u16* vt    = (u16*)(ws + 40 * MB);     // full V^T overlays dead kb
    u16* biasp = (u16*)(ws + 96 * MB);
    u16* p0   = xb;                        // m-half-0 partial O
    u16* p1   = vb;                        // m-half-1 partial O; becomes ao
    u16* ao   = p1;
    u16* t0   = qb;
    u16* fh   = kb;
    u16* w1T  = (u16*)(ws + 72 * MB);      // overlay kt post-attention
    u16* w2T  = (u16*)(ws + 80 * MB);
    u16* pre2 = (u16*)(ws + 88 * MB);

    dim3 blk(256);
    const long M1 = 1048576;

    // phase 0: conversions (wq|wk|wv|wc in ONE launch; dst contiguous)
    convert_f2b<<<dim3(8192), blk, 0, stream>>>(xf, xb);
    transpose4_f2b<<<dim3(32, 32, 4), blk, 0, stream>>>(wq, wk, wv, wc, wqkvT);
    pack_bias<<<dim3(36), blk, 0, stream>>>(bq, bk, bv, bc, b1, b2, biasp);

    // phase 1: fused QKV (Q projection pre-scaled by 0.125*log2e: z==0 only)
    gemm_bt<128><<<dim3(8, 64, 3), blk, 0, stream>>>(
        xb, 0, 1024, wqkvT, M1, 1024, qb, 8 * M1, 1024, 1024,
        biasp, 1024, nullptr, 0, 0, QSCALE, 1, 0);

    // phase 2: kt = reshape-view K_t transposed to [m][d], all (b,h)
    //          (must precede vt, which overwrites kb)
    transpose_bf<<<dim3(32, 2, 128), blk, 0, stream>>>(kb, kt, 64, 1024);

    // phase 3: full V^T, then 1024-block fused attention (XCD-swizzled, 4-wave)
    transpose_bf<<<dim3(2, 32, 128), blk, 0, stream>>>(vb, vt, 1024, 64);
    attn_fused<<<dim3(1024), blk, 0, stream>>>(qb, kt, vt, mask, p0, p1);
    // partial-O reduction: ao := p0 + p1 (in-place into p1)
    add_bf<<<dim3(4096), blk, 0, stream>>>(p0, p1);

    // phase 4: out-proj + bias + resid(x) -> t0 ; LN1 in-place
    gemm_bt<128><<<dim3(8, 64, 1), blk, 0, stream>>>(
        ao, 0, 1024, wcT, 0, 1024, t0, 0, 1024, 1024,
        biasp + 3072, 0, xf, 1, 0, 1.f, 0, 0);
    layernorm_row<<<dim3(2048), blk, 0, stream>>>(t0, g1, be1, t0, 0);

    // phase 5: FFN weight transposes into dead kt region
    transpose_f2b<<<dim3(128, 32), blk, 0, stream>>>(w1, w1T, 1024, 4096);
    transpose_f2b<<<dim3(32, 128), blk, 0, stream>>>(w2, w2T, 4096, 1024);

    // phase 6: FFN + LN2, 2 chunks of 4096 rows
    for (int c = 0; c < 2; ++c) {
        long r0 = (long)c * 4096 * 1024;
        gemm_bt<128><<<dim3(32, 32, 1), blk, 0, stream>>>(
            t0 + r0, 0, 1024, w1T, 0, 1024, fh, 0, 4096, 1024,
            biasp + 4096, 0, nullptr, 0, 0, 1.f, 0, 1);
        gemm_bt<64><<<dim3(16, 32, 1), blk, 0, stream>>>(
            fh, 0, 4096, w2T, 0, 4096, pre2, 0, 1024, 4096,
            biasp + 8192, 0, t0 + r0, 0, 0, 1.f, 0, 0);
        layernorm_row<<<dim3(1024), blk, 0, stream>>>(
            pre2, g2, be2, (float*)d_out + r0, 1);
    }
}

// Round 11
// 925.467 us; speedup vs baseline: 1.0505x; 1.0505x over previous
//
#include <hip/hip_runtime.h>
#include <stdint.h>

typedef unsigned short u16;
typedef __attribute__((ext_vector_type(8))) short sx8;   // 8 bf16 (4 VGPRs) — MFMA A/B frag
typedef __attribute__((ext_vector_type(4))) float fx4;   // MFMA C/D frag

__device__ __forceinline__ float bf2f(u16 u) {
    union { unsigned i; float f; } v; v.i = ((unsigned)u) << 16; return v.f;
}
__device__ __forceinline__ u16 f2bf(float f) {
    union { float f; unsigned i; } v; v.f = f;
    return (u16)((v.i + 0x7FFFu + ((v.i >> 16) & 1u)) >> 16);
}
#define MFMA(a, b, c) __builtin_amdgcn_mfma_f32_16x16x32_bf16((a), (b), (c), 0, 0, 0)

#define GLDS(gp, lp) \
    __builtin_amdgcn_global_load_lds((const __attribute__((address_space(1))) void*)(gp), \
                                     (__attribute__((address_space(3))) void*)(lp), 16, 0, 0)

// 0.125 (1/sqrt(64)) * log2(e): attention scale folded with the exp->exp2
// domain change. Softmax keeps max-subtraction (sum >= 1, NaN-proof);
// 2^(S'-mx)/sum equals natural-exp softmax exactly (base change cancels).
#define QSCALE 0.18033688011112042f
// masked score -1e-12 nats -> log2 domain
#define MASKC (-1.442695e-12f)

// ---------- m97-style MFMA GEMM: C[M,N] = A[M,K] @ BT[N,K]^T, all bf16 ----------
// Proven BK=32 form (R9's BK=64 regressed: drain cost scales with outstanding
// loads, so halving barrier events bought nothing).
// scaleZ0: when set, `scale` applies only to batch z==0 (folds the attention
// scale into the Q projection of the fused QKV GEMM).
template<int BN>
__global__ __launch_bounds__(256) void gemm_bt(
    const u16* __restrict__ A, long sA, int ldA,
    const u16* __restrict__ BT, long sBT, int ldBT,
    u16* __restrict__ C, long sC, int ldC,
    int K,
    const u16* __restrict__ bias, int bz,
    const void* __restrict__ resid, int residF32, long rofs,
    float scale, int scaleZ0, int relu)
{
    constexpr int BK = 32;
    constexpr int TM = 4;
    constexpr int TN = BN / 32;
    constexpr int AI = 2;
    constexpr int BI = BN / 64;

    __shared__ __align__(16) u16 As[128 * BK];
    __shared__ __align__(16) u16 Bs[BN * BK];

    const int tid  = threadIdx.x;
    const int w    = tid >> 6;
    const int lane = tid & 63;
    const int quad = lane >> 4;
    const int n16  = lane & 15;
    const int wrow = w >> 1, wcol = w & 1;

    // XCD-chunked swizzle over the (x,y) plane (bijective when nxy%8==0)
    int bx = blockIdx.x, by = blockIdx.y;
    {
        int nxy = gridDim.x * gridDim.y;
        if ((nxy & 7) == 0) {
            int bid = by * gridDim.x + bx;
            int wgs = (bid & 7) * (nxy >> 3) + (bid >> 3);
            bx = wgs % gridDim.x;
            by = wgs / gridDim.x;
        }
    }
    const int m0 = by * 128, n0 = bx * BN;
    const long z = blockIdx.z;
    const float es = (z == 0 || !scaleZ0) ? scale : 1.f;
    A  += z * sA;
    BT += z * sBT;
    C  += z * sC;

    fx4 acc[TM][TN] = {};

    for (int k0 = 0; k0 < K; k0 += BK) {
        #pragma unroll
        for (int i = 0; i < AI; ++i) {
            unsigned base = (unsigned)(w * AI + i) * 1024u;
            unsigned off  = base + (unsigned)lane * 16u;
            unsigned row  = off >> 6;
            unsigned col  = (off & 63u) >> 1;
            GLDS(A + (long)(m0 + row) * ldA + k0 + col, (char*)As + base);
        }
        #pragma unroll
        for (int i = 0; i < BI; ++i) {
            unsigned base = (unsigned)(w * BI + i) * 1024u;
            unsigned off  = base + (unsigned)lane * 16u;
            unsigned row  = off >> 6;
            unsigned col  = (off & 63u) >> 1;
            GLDS(BT + (long)(n0 + row) * ldBT + k0 + col, (char*)Bs + base);
        }
        __syncthreads();

        sx8 af[TM], bfr[TN];
        #pragma unroll
        for (int r = 0; r < TM; ++r)
            af[r] = *(const sx8*)&As[(wrow * 64 + r * 16 + n16) * BK + quad * 8];
        #pragma unroll
        for (int c = 0; c < TN; ++c)
            bfr[c] = *(const sx8*)&Bs[(wcol * (TN * 16) + c * 16 + n16) * BK + quad * 8];
        #pragma unroll
        for (int r = 0; r < TM; ++r)
            #pragma unroll
            for (int c = 0; c < TN; ++c)
                acc[r][c] = MFMA(af[r], bfr[c], acc[r][c]);
        __syncthreads();
    }

    #pragma unroll
    for (int r = 0; r < TM; ++r) {
        int row = m0 + wrow * 64 + r * 16 + quad * 4;
        #pragma unroll
        for (int c = 0; c < TN; ++c) {
            int col = n0 + wcol * (TN * 16) + c * 16 + n16;
            float bv = bias ? bf2f(bias[bz * (int)z + col]) : 0.f;
            #pragma unroll
            for (int g = 0; g < 4; ++g) {
                long idx = (long)(row + g) * ldC + col;
                float xv = acc[r][c][g] * es + bv;
                if (resid)
                    xv += residF32 ? ((const float*)resid)[rofs + idx]
                                   : bf2f(((const u16*)resid)[rofs + idx]);
                if (relu) xv = fmaxf(xv, 0.f);
                C[idx] = f2bf(xv);
            }
        }
    }
}

// ---------- fused attention: S'=(Q*QSCALE)@Kt, head-softmax (exp2+max), O=PV ----------
// FROZEN R8 configuration — the measured best (925 us total, attn ~302 us).
// Ledger (R1-R10): attn is insensitive to occupancy (23/45/57%), FETCH
// (41->385 MB), and softmax VALU count (-35% slots -> 0 delta); barrier-free
// restructure -2.1x; chunk rotation -8% (L2 thrash, R10). The ~300us is the
// 3-barrier LDS-round-trip structure's intra-block dependency latency.
// In-sequence chunk order (identical across resident blocks) is REQUIRED:
// it makes same-XCD blocks stream the same K/V chunk simultaneously (L2 share).
// Internals: exp2+max-sub softmax (NaN-proof), f2bf S-store (MFMA->asm-VALU
// hazard avoidance: cvt_pk asm on raw MFMA results was the R6/R7 NaN),
// cvt_pk P-store on plain-VALU inputs, rcpf, mask prefetch, XCD-chunked
// swizzle, 2-way m-split + add_bf reduction.
// qb [b][16h][1024 l][64 d]; kt [(b,h)][m][d] reshape-view K_t; vt [b][16h][64 d][1024 m].
__global__ __launch_bounds__(256, 4) void attn_fused(
    const u16* __restrict__ qb, const u16* __restrict__ kt,
    const u16* __restrict__ vt, const int* __restrict__ mask,
    u16* __restrict__ p0, u16* __restrict__ p1)
{
    constexpr int MC = 64;           // m-chunk
    constexpr int LM = MC + 8;       // 72 (pad; rows stay 16B-aligned: 144B stride)
    constexpr int SH = 16 * LM;      // per-head stride = 1152 u16
    __shared__ __align__(16) u16 Ss[16 * SH];   // 36,864 B

    const int tid = threadIdx.x, w = tid >> 6, lane = tid & 63;
    const int quad = lane >> 4, n16 = lane & 15;

    // XCD-chunked swizzle (1024 blocks, 8 XCDs, bijective)
    const int wg = ((blockIdx.x & 7) << 7) + (blockIdx.x >> 3);
    const int l0 = (wg & 63) * 16;
    const long bo = (long)((wg >> 6) & 7) * 1048576;
    const int zz = wg >> 9;
    const int mbase = zz * 512;
    u16* __restrict__ po = zz ? p1 : p0;

    // softmax work split: thread covers (l, m-pair) p = tid + 256*j
    const int sl0 = tid >> 5,         smp0 = (tid & 31) * 2;
    const int sl1 = (tid + 256) >> 5, smp1 = ((tid + 256) & 31) * 2;

    // resident Q B-frags for this wave's 4 heads (col=l, k=d); Q pre-scaled
    sx8 qf[4][2];
    #pragma unroll
    for (int i = 0; i < 4; ++i) {
        const u16* qp = qb + bo + (w * 4 + i) * 65536 + (l0 + n16) * 64 + quad * 8;
        qf[i][0] = *(const sx8*)qp;
        qf[i][1] = *(const sx8*)(qp + 32);
    }

    fx4 of[4][4] = {};   // partial-O accumulators [head][d-tile]

    for (int mt = 0; mt < 8; ++mt) {
        const int m0 = mbase + mt * MC;
        // ---- mask prefetch (plain loads; complete by the QK->softmax barrier) ----
        const int2 mk0 = *(const int2*)&mask[bo + (long)(l0 + sl0) * 1024 + m0 + smp0];
        const int2 mk1 = *(const int2*)&mask[bo + (long)(l0 + sl1) * 1024 + m0 + smp1];
        // ---- S'^T = K @ Qs^T : A-frag rows = m (from kt), B-frag cols = l ----
        #pragma unroll
        for (int i = 0; i < 4; ++i) {
            const int h = w * 4 + i;
            const u16* kp = kt + bo + h * 65536 + (long)m0 * 64;
            #pragma unroll
            for (int nt = 0; nt < 4; ++nt) {
                const u16* kr = kp + (nt * 16 + n16) * 64 + quad * 8;
                fx4 s = {};
                s = MFMA(*(const sx8*)kr,        qf[i][0], s);
                s = MFMA(*(const sx8*)(kr + 32), qf[i][1], s);
                // D: row = m = quad*4 + reg (consecutive), col = l = n16
                // f2bf IR path (NOT asm): compiler inserts the MFMA->VALU hazard waits
                uint2 pk;
                pk.x = (unsigned)f2bf(s[0]) | ((unsigned)f2bf(s[1]) << 16);
                pk.y = (unsigned)f2bf(s[2]) | ((unsigned)f2bf(s[3]) << 16);
                *(uint2*)&Ss[h * SH + n16 * LM + nt * 16 + quad * 4] = pk;
            }
        }
        __syncthreads();
        // ---- softmax over 16 heads, pointwise in (l,m); exp2 domain + max-sub ----
        // pair-packed: 16 l x 32 m-pairs = 512 positions, 2 per thread.
        #pragma unroll
        for (int j = 0; j < 2; ++j) {
            const int l = j ? sl1 : sl0, mp = j ? smp1 : smp0;
            const int2 mk = j ? mk1 : mk0;
            u16* col = &Ss[l * LM + mp];
            float v0[16], v1[16], mx0 = -1e30f, mx1 = -1e30f;
            #pragma unroll
            for (int h = 0; h < 16; ++h) {
                unsigned pr = *(const unsigned*)&col[h * SH];
                float a = (mk.x == 0) ? MASKC : bf2f((u16)(pr & 0xffff));
                float b = (mk.y == 0) ? MASKC : bf2f((u16)(pr >> 16));
                v0[h] = a; v1[h] = b;
                mx0 = fmaxf(mx0, a); mx1 = fmaxf(mx1, b);
            }
            float s0 = 0.f, s1 = 0.f;
            #pragma unroll
            for (int h = 0; h < 16; ++h) {
                v0[h] = exp2f(v0[h] - mx0); s0 += v0[h];
                v1[h] = exp2f(v1[h] - mx1); s1 += v1[h];
            }
            const float i0 = __builtin_amdgcn_rcpf(s0);
            const float i1 = __builtin_amdgcn_rcpf(s1);
            #pragma unroll
            for (int h = 0; h < 16; ++h) {
                // cvt_pk on plain VALU inputs — R4/R8-proven pattern
                float e0 = v0[h] * i0, e1 = v1[h] * i1;
                unsigned pk_;
                asm("v_cvt_pk_bf16_f32 %0, %1, %2" : "=v"(pk_) : "v"(e0), "v"(e1));
                *(unsigned*)&col[h * SH] = pk_;
            }
        }
        __syncthreads();
        // ---- O += P @ V (A-frag rows = l from Ss, B-frag from vt, m contiguous) ----
        #pragma unroll
        for (int i = 0; i < 4; ++i) {
            const int h = w * 4 + i;
            const u16* sp = &Ss[h * SH + n16 * LM];
            sx8 a0 = *(const sx8*)(sp + quad * 8);
            sx8 a1 = *(const sx8*)(sp + 32 + quad * 8);
            const u16* vp = vt + bo + h * 65536 + (long)n16 * 1024 + m0 + quad * 8;
            #pragma unroll
            for (int dt = 0; dt < 4; ++dt) {
                of[i][dt] = MFMA(a0, *(const sx8*)(vp + dt * 16384),      of[i][dt]);
                of[i][dt] = MFMA(a1, *(const sx8*)(vp + dt * 16384 + 32), of[i][dt]);
            }
        }
        __syncthreads();
    }

    // ---- epilogue: head-major flat store of this half's partial O ----
    #pragma unroll
    for (int i = 0; i < 4; ++i) {
        const int h = w * 4 + i;
        #pragma unroll
        for (int dt = 0; dt < 4; ++dt)
            #pragma unroll
            for (int r = 0; r < 4; ++r)
                po[bo + h * 65536 + (long)(l0 + quad * 4 + r) * 64 + dt * 16 + n16]
                    = f2bf(of[i][dt][r]);
    }
}

// ---------- bf16 partial-O reduction: b := bf16(a + b), element-wise in-place ----------
__global__ __launch_bounds__(256) void add_bf(
    const u16* __restrict__ a, u16* __restrict__ b)
{
    long i = ((long)blockIdx.x * 256 + threadIdx.x) * 8;
    uint4 x = *(const uint4*)(a + i);
    uint4 y = *(const uint4*)(b + i);
    uint4 r;
    unsigned* xp = (unsigned*)&x; unsigned* yp = (unsigned*)&y; unsigned* rp = (unsigned*)&r;
    #pragma unroll
    for (int k = 0; k < 4; ++k) {
        float lo = bf2f((u16)(xp[k] & 0xffff)) + bf2f((u16)(yp[k] & 0xffff));
        float hi = bf2f((u16)(xp[k] >> 16))    + bf2f((u16)(yp[k] >> 16));
        rp[k] = (unsigned)f2bf(lo) | ((unsigned)f2bf(hi) << 16);
    }
    *(uint4*)(b + i) = r;
}

// ---------- fp32 -> bf16 elementwise ----------
__global__ __launch_bounds__(256) void convert_f2b(
    const float* __restrict__ in, u16* __restrict__ out)
{
    long i = ((long)blockIdx.x * 256 + threadIdx.x) * 4;
    fx4 v = *(const fx4*)(in + i);
    uint2 o;
    o.x = (unsigned)f2bf(v[0]) | ((unsigned)f2bf(v[1]) << 16);
    o.y = (unsigned)f2bf(v[2]) | ((unsigned)f2bf(v[3]) << 16);
    *(uint2*)(out + i) = o;
}

// ---------- 4x fp32 [1024][1024] -> bf16 transposed, one launch (z selects src) ----------
__global__ __launch_bounds__(256) void transpose4_f2b(
    const float* a0, const float* a1, const float* a2, const float* a3,
    u16* __restrict__ out)
{
    __shared__ float t[32][33];
    const float* in = blockIdx.z == 0 ? a0 : blockIdx.z == 1 ? a1
                    : blockIdx.z == 2 ? a2 : a3;
    out += (long)blockIdx.z * 1048576;
    int c0 = blockIdx.x * 32, r0 = blockIdx.y * 32;
    int tx = threadIdx.x & 31, ty = threadIdx.x >> 5;
    #pragma unroll
    for (int i = 0; i < 4; ++i)
        t[ty + i * 8][tx] = in[(long)(r0 + ty + i * 8) * 1024 + c0 + tx];
    __syncthreads();
    #pragma unroll
    for (int i = 0; i < 4; ++i)
        out[(long)(c0 + ty + i * 8) * 1024 + r0 + tx] = f2bf(t[tx][ty + i * 8]);
}

// ---------- fp32 [R][C] -> bf16 transposed [C][R] ----------
__global__ __launch_bounds__(256) void transpose_f2b(
    const float* __restrict__ in, u16* __restrict__ out, int R, int C)
{
    __shared__ float t[32][33];
    int c0 = blockIdx.x * 32, r0 = blockIdx.y * 32;
    int tx = threadIdx.x & 31, ty = threadIdx.x >> 5;
    #pragma unroll
    for (int i = 0; i < 4; ++i)
        t[ty + i * 8][tx] = in[(long)(r0 + ty + i * 8) * C + c0 + tx];
    __syncthreads();
    #pragma unroll
    for (int i = 0; i < 4; ++i)
        out[(long)(c0 + ty + i * 8) * R + r0 + tx] = f2bf(t[tx][ty + i * 8]);
}

// ---------- bf16 batched transpose ----------
__global__ __launch_bounds__(256) void transpose_bf(
    const u16* __restrict__ in, u16* __restrict__ out, int R, int C)
{
    __shared__ u16 t[32][33];
    long zoff = (long)blockIdx.z * (long)R * (long)C;
    in += zoff; out += zoff;
    int c0 = blockIdx.x * 32, r0 = blockIdx.y * 32;
    int tx = threadIdx.x & 31, ty = threadIdx.x >> 5;
    #pragma unroll
    for (int i = 0; i < 4; ++i)
        t[ty + i * 8][tx] = in[(long)(r0 + ty + i * 8) * C + c0 + tx];
    __syncthreads();
    #pragma unroll
    for (int i = 0; i < 4; ++i)
        out[(long)(c0 + ty + i * 8) * R + r0 + tx] = t[tx][ty + i * 8];
}

// ---------- pack biases fp32 -> bf16 [bq|bk|bv|bc|b1|b2]; bq pre-scaled QSCALE ----------
__global__ __launch_bounds__(256) void pack_bias(
    const float* bq, const float* bk, const float* bv, const float* bc,
    const float* b1, const float* b2, u16* __restrict__ out)
{
    int i = blockIdx.x * 256 + threadIdx.x;
    float v;
    if      (i < 1024) v = bq[i] * QSCALE;
    else if (i < 2048) v = bk[i - 1024];
    else if (i < 3072) v = bv[i - 2048];
    else if (i < 4096) v = bc[i - 3072];
    else if (i < 8192) v = b1[i - 4096];
    else               v = b2[i - 8192];
    out[i] = f2bf(v);
}

// ---------- LayerNorm (ddof=1, /(std+eps)) ----------
__global__ __launch_bounds__(256) void layernorm_row(
    const u16* __restrict__ in, const float* __restrict__ g,
    const float* __restrict__ be, void* __restrict__ out, int outF32)
{
    int wave = threadIdx.x >> 6, lane = threadIdx.x & 63;
    long row = (long)blockIdx.x * 4 + wave;
    const u16* p = in + row * 1024 + lane * 16;

    float x[16];
    uint4 a = ((const uint4*)p)[0], b = ((const uint4*)p)[1];
    {
        unsigned u;
        u = a.x; x[0] = bf2f(u & 0xffff);  x[1] = bf2f(u >> 16);
        u = a.y; x[2] = bf2f(u & 0xffff);  x[3] = bf2f(u >> 16);
        u = a.z; x[4] = bf2f(u & 0xffff);  x[5] = bf2f(u >> 16);
        u = a.w; x[6] = bf2f(u & 0xffff);  x[7] = bf2f(u >> 16);
        u = b.x; x[8] = bf2f(u & 0xffff);  x[9] = bf2f(u >> 16);
        u = b.y; x[10] = bf2f(u & 0xffff); x[11] = bf2f(u >> 16);
        u = b.z; x[12] = bf2f(u & 0xffff); x[13] = bf2f(u >> 16);
        u = b.w; x[14] = bf2f(u & 0xffff); x[15] = bf2f(u >> 16);
    }
    float s = 0.f, ss = 0.f;
    #pragma unroll
    for (int i = 0; i < 16; ++i) { s += x[i]; ss += x[i] * x[i]; }
    #pragma unroll
    for (int o = 32; o >= 1; o >>= 1) { s += __shfl_down(s, o); ss += __shfl_down(ss, o); }
    s = __shfl(s, 0); ss = __shfl(ss, 0);
    float mean = s * (1.f / 1024.f);
    float var  = fmaxf((ss - 1024.f * mean * mean) * (1.f / 1023.f), 0.f);
    float rinv = 1.f / (sqrtf(var) + 1e-12f);

    int col = lane * 16;
    if (outF32) {
        float* ov = (float*)out + row * 1024 + col;
        #pragma unroll
        for (int i = 0; i < 16; ++i)
            ov[i] = g[col + i] * ((x[i] - mean) * rinv) + be[col + i];
    } else {
        u16* ov = (u16*)out + row * 1024 + col;
        #pragma unroll
        for (int i = 0; i < 16; ++i)
            ov[i] = f2bf(g[col + i] * ((x[i] - mean) * rinv) + be[col + i]);
    }
}

// ---------- launch ----------
// ws map (MB; peak 96 + 18KB bias):
//  [0,16)  xb -> p0 (m-half-0 partial O)
//  [16,22) wqkvT  [22,24) wcT (contiguous: one transpose4 launch)
//  [24,40) qb -> t0/x1
//  [40,56) kb -> vt (full V^T over dead kb) -> fh lower
//  [56,72) vb -> p1 (m-half-1 partial O) -> ao (after add_bf) -> fh upper
//  [72,88) kt (reshape-view K_t, all b) -> w1T/w2T post-attention
//  [88,96) pre2 (FFN phase; free during attention)
//  [96,+18KB) packed biases
extern "C" void kernel_launch(void* const* d_in, const int* in_sizes, int n_in,
                              void* d_out, int out_size, void* d_ws, size_t ws_size,
                              hipStream_t stream)
{
    const float* xf  = (const float*)d_in[0];
    const int* mask  = (const int*)d_in[1];
    const float* wq = (const float*)d_in[2];  const float* bq = (const float*)d_in[3];
    const float* wk = (const float*)d_in[4];  const float* bk = (const float*)d_in[5];
    const float* wv = (const float*)d_in[6];  const float* bv = (const float*)d_in[7];
    const float* wc = (const float*)d_in[8];  const float* bc = (const float*)d_in[9];
    const float* g1 = (const float*)d_in[10]; const float* be1 = (const float*)d_in[11];
    const float* w1 = (const float*)d_in[12]; const float* b1 = (const float*)d_in[13];
    const float* w2 = (const float*)d_in[14]; const float* b2 = (const float*)d_in[15];
    const float* g2 = (const float*)d_in[16]; const float* be2 = (const float*)d_in[17];

    char* ws = (char*)d_ws;
    const long MB = 1 << 20;
    u16* xb    = (u16*)(ws + 0 * MB);
    u16* wqkvT = (u16*)(ws + 16 * MB);
    u16* wcT   = (u16*)(ws + 22 * MB);
    u16* qb    = (u16*)(ws + 24 * MB);
    u16* kb    = (u16*)(ws + 40 * MB);
    u16* vb    = (u16*)(ws + 56 * MB);
    u16* kt    = (u16*)(ws + 72 * MB);
    u16* vt    = (u16*)(ws + 40 * MB);     // full V^T overlays dead kb
    u16* biasp = (u16*)(ws + 96 * MB);
    u16* p0   = xb;                        // m-half-0 partial O
    u16* p1   = vb;                        // m-half-1 partial O; becomes ao
    u16* ao   = p1;
    u16* t0   = qb;
    u16* fh   = kb;
    u16* w1T  = (u16*)(ws + 72 * MB);      // overlay kt post-attention
    u16* w2T  = (u16*)(ws + 80 * MB);
    u16* pre2 = (u16*)(ws + 88 * MB);

    dim3 blk(256);
    const long M1 = 1048576;

    // phase 0: conversions (wq|wk|wv|wc in ONE launch; dst contiguous)
    convert_f2b<<<dim3(8192), blk, 0, stream>>>(xf, xb);
    transpose4_f2b<<<dim3(32, 32, 4), blk, 0, stream>>>(wq, wk, wv, wc, wqkvT);
    pack_bias<<<dim3(36), blk, 0, stream>>>(bq, bk, bv, bc, b1, b2, biasp);

    // phase 1: fused QKV (Q projection pre-scaled by 0.125*log2e: z==0 only)
    gemm_bt<128><<<dim3(8, 64, 3), blk, 0, stream>>>(
        xb, 0, 1024, wqkvT, M1, 1024, qb, 8 * M1, 1024, 1024,
        biasp, 1024, nullptr, 0, 0, QSCALE, 1, 0);

    // phase 2: kt = reshape-view K_t transposed to [m][d], all (b,h)
    //          (must precede vt, which overwrites kb)
    transpose_bf<<<dim3(32, 2, 128), blk, 0, stream>>>(kb, kt, 64, 1024);

    // phase 3: full V^T, then 1024-block fused attention (XCD-swizzled, 4-wave)
    transpose_bf<<<dim3(2, 32, 128), blk, 0, stream>>>(vb, vt, 1024, 64);
    attn_fused<<<dim3(1024), blk, 0, stream>>>(qb, kt, vt, mask, p0, p1);
    // partial-O reduction: ao := p0 + p1 (in-place into p1)
    add_bf<<<dim3(4096), blk, 0, stream>>>(p0, p1);

    // phase 4: out-proj + bias + resid(x) -> t0 ; LN1 in-place
    gemm_bt<128><<<dim3(8, 64, 1), blk, 0, stream>>>(
        ao, 0, 1024, wcT, 0, 1024, t0, 0, 1024, 1024,
        biasp + 3072, 0, xf, 1, 0, 1.f, 0, 0);
    layernorm_row<<<dim3(2048), blk, 0, stream>>>(t0, g1, be1, t0, 0);

    // phase 5: FFN weight transposes into dead kt region
    transpose_f2b<<<dim3(128, 32), blk, 0, stream>>>(w1, w1T, 1024, 4096);
    transpose_f2b<<<dim3(32, 128), blk, 0, stream>>>(w2, w2T, 4096, 1024);

    // phase 6: FFN + LN2, 2 chunks of 4096 rows
    for (int c = 0; c < 2; ++c) {
        long r0 = (long)c * 4096 * 1024;
        gemm_bt<128><<<dim3(32, 32, 1), blk, 0, stream>>>(
            t0 + r0, 0, 1024, w1T, 0, 1024, fh, 0, 4096, 1024,
            biasp + 4096, 0, nullptr, 0, 0, 1.f, 0, 1);
        gemm_bt<64><<<dim3(16, 32, 1), blk, 0, stream>>>(
            fh, 0, 4096, w2T, 0, 4096, pre2, 0, 1024, 4096,
            biasp + 8192, 0, t0 + r0, 0, 0, 1.f, 0, 0);
        layernorm_row<<<dim3(1024), blk, 0, stream>>>(
            pre2, g2, be2, (float*)d_out + r0, 1);
    }
}

// Round 12
// 900.777 us; speedup vs baseline: 1.0793x; 1.0274x over previous
//
#include <hip/hip_runtime.h>
#include <stdint.h>

typedef unsigned short u16;
typedef __attribute__((ext_vector_type(8))) short sx8;   // 8 bf16 (4 VGPRs) — MFMA A/B frag
typedef __attribute__((ext_vector_type(4))) float fx4;   // MFMA C/D frag

__device__ __forceinline__ float bf2f(u16 u) {
    union { unsigned i; float f; } v; v.i = ((unsigned)u) << 16; return v.f;
}
__device__ __forceinline__ u16 f2bf(float f) {
    union { float f; unsigned i; } v; v.f = f;
    return (u16)((v.i + 0x7FFFu + ((v.i >> 16) & 1u)) >> 16);
}
#define MFMA(a, b, c) __builtin_amdgcn_mfma_f32_16x16x32_bf16((a), (b), (c), 0, 0, 0)

#define GLDS(gp, lp) \
    __builtin_amdgcn_global_load_lds((const __attribute__((address_space(1))) void*)(gp), \
                                     (__attribute__((address_space(3))) void*)(lp), 16, 0, 0)

// 0.125 (1/sqrt(64)) * log2(e): attention scale folded with the exp->exp2
// domain change. Softmax keeps max-subtraction (sum >= 1, NaN-proof);
// 2^(S'-mx)/sum equals natural-exp softmax exactly (base change cancels).
#define QSCALE 0.18033688011112042f
// masked score -1e-12 nats -> log2 domain
#define MASKC (-1.442695e-12f)

// ---------- m97-style MFMA GEMM: C[M,N] = A[M,K] @ BT[N,K]^T, all bf16 ----------
// Proven BK=32 form. scaleZ0: `scale` applies only to batch z==0 (folds the
// attention scale into the Q projection of the fused QKV GEMM).
template<int BN>
__global__ __launch_bounds__(256) void gemm_bt(
    const u16* __restrict__ A, long sA, int ldA,
    const u16* __restrict__ BT, long sBT, int ldBT,
    u16* __restrict__ C, long sC, int ldC,
    int K,
    const u16* __restrict__ bias, int bz,
    const void* __restrict__ resid, int residF32, long rofs,
    float scale, int scaleZ0, int relu)
{
    constexpr int BK = 32;
    constexpr int TM = 4;
    constexpr int TN = BN / 32;
    constexpr int AI = 2;
    constexpr int BI = BN / 64;

    __shared__ __align__(16) u16 As[128 * BK];
    __shared__ __align__(16) u16 Bs[BN * BK];

    const int tid  = threadIdx.x;
    const int w    = tid >> 6;
    const int lane = tid & 63;
    const int quad = lane >> 4;
    const int n16  = lane & 15;
    const int wrow = w >> 1, wcol = w & 1;

    // XCD-chunked swizzle over the (x,y) plane (bijective when nxy%8==0)
    int bx = blockIdx.x, by = blockIdx.y;
    {
        int nxy = gridDim.x * gridDim.y;
        if ((nxy & 7) == 0) {
            int bid = by * gridDim.x + bx;
            int wgs = (bid & 7) * (nxy >> 3) + (bid >> 3);
            bx = wgs % gridDim.x;
            by = wgs / gridDim.x;
        }
    }
    const int m0 = by * 128, n0 = bx * BN;
    const long z = blockIdx.z;
    const float es = (z == 0 || !scaleZ0) ? scale : 1.f;
    A  += z * sA;
    BT += z * sBT;
    C  += z * sC;

    fx4 acc[TM][TN] = {};

    for (int k0 = 0; k0 < K; k0 += BK) {
        #pragma unroll
        for (int i = 0; i < AI; ++i) {
            unsigned base = (unsigned)(w * AI + i) * 1024u;
            unsigned off  = base + (unsigned)lane * 16u;
            unsigned row  = off >> 6;
            unsigned col  = (off & 63u) >> 1;
            GLDS(A + (long)(m0 + row) * ldA + k0 + col, (char*)As + base);
        }
        #pragma unroll
        for (int i = 0; i < BI; ++i) {
            unsigned base = (unsigned)(w * BI + i) * 1024u;
            unsigned off  = base + (unsigned)lane * 16u;
            unsigned row  = off >> 6;
            unsigned col  = (off & 63u) >> 1;
            GLDS(BT + (long)(n0 + row) * ldBT + k0 + col, (char*)Bs + base);
        }
        __syncthreads();

        sx8 af[TM], bfr[TN];
        #pragma unroll
        for (int r = 0; r < TM; ++r)
            af[r] = *(const sx8*)&As[(wrow * 64 + r * 16 + n16) * BK + quad * 8];
        #pragma unroll
        for (int c = 0; c < TN; ++c)
            bfr[c] = *(const sx8*)&Bs[(wcol * (TN * 16) + c * 16 + n16) * BK + quad * 8];
        #pragma unroll
        for (int r = 0; r < TM; ++r)
            #pragma unroll
            for (int c = 0; c < TN; ++c)
                acc[r][c] = MFMA(af[r], bfr[c], acc[r][c]);
        __syncthreads();
    }

    #pragma unroll
    for (int r = 0; r < TM; ++r) {
        int row = m0 + wrow * 64 + r * 16 + quad * 4;
        #pragma unroll
        for (int c = 0; c < TN; ++c) {
            int col = n0 + wcol * (TN * 16) + c * 16 + n16;
            float bv = bias ? bf2f(bias[bz * (int)z + col]) : 0.f;
            #pragma unroll
            for (int g = 0; g < 4; ++g) {
                long idx = (long)(row + g) * ldC + col;
                float xv = acc[r][c][g] * es + bv;
                if (resid)
                    xv += residF32 ? ((const float*)resid)[rofs + idx]
                                   : bf2f(((const u16*)resid)[rofs + idx]);
                if (relu) xv = fmaxf(xv, 0.f);
                C[idx] = f2bf(xv);
            }
        }
    }
}

// ---------- fused attention: phase-merged pipeline (R12) ----------
// R12 = R8 internals + restructured main loop. The ledger (R1-R11) pinned
// attn's ~292us on the serialized 3-phase chain QK->bar->softmax->bar->PV->bar
// (all pipes <25% busy; occupancy/FETCH/VALU-count levers all null). QK(t+1)
// and softmax(t) are INDEPENDENT (disjoint S buffers), so with double-buffered
// Ss they share one inter-barrier region: QK's MFMAs issue on the matrix pipe
// while softmax's exp2/fmax chain issues on the VALU — QK leaves the critical
// path, and barriers drop 3->2 per iter.
//   QK(0); bar;  for t: { [QK(t+1) || softmax(t)]; bar; PV(t); bar }
// Chunk order stays in-sequence across blocks (R10: rotation thrashed L2).
// Cost: Ss x2 = 73.7KB -> 2 blocks/CU (23% occ) — weakest proven lever.
// Numerics identical to R8 (pure reordering). f2bf IR path on MFMA outputs
// (MFMA->asm-VALU hazard = R6/R7 NaN); cvt_pk only on plain-VALU inputs.
// qb [b][16h][1024 l][64 d]; kt [(b,h)][m][d] reshape-view K_t; vt [b][16h][64 d][1024 m].
__global__ __launch_bounds__(256, 2) void attn_fused(
    const u16* __restrict__ qb, const u16* __restrict__ kt,
    const u16* __restrict__ vt, const int* __restrict__ mask,
    u16* __restrict__ p0, u16* __restrict__ p1)
{
    constexpr int MC = 64;           // m-chunk
    constexpr int LM = MC + 8;       // 72 (pad; rows stay 16B-aligned: 144B stride)
    constexpr int SH = 16 * LM;      // per-head stride = 1152 u16
    __shared__ __align__(16) u16 Ss[2][16 * SH];   // 2 x 36,864 B = 73,728 B

    const int tid = threadIdx.x, w = tid >> 6, lane = tid & 63;
    const int quad = lane >> 4, n16 = lane & 15;

    // XCD-chunked swizzle (1024 blocks, 8 XCDs, bijective)
    const int wg = ((blockIdx.x & 7) << 7) + (blockIdx.x >> 3);
    const int l0 = (wg & 63) * 16;
    const long bo = (long)((wg >> 6) & 7) * 1048576;
    const int zz = wg >> 9;
    const int mbase = zz * 512;
    u16* __restrict__ po = zz ? p1 : p0;

    // softmax work split: thread covers (l, m-pair) p = tid + 256*j
    const int sl0 = tid >> 5,         smp0 = (tid & 31) * 2;
    const int sl1 = (tid + 256) >> 5, smp1 = ((tid + 256) & 31) * 2;

    // resident Q B-frags for this wave's 4 heads (col=l, k=d); Q pre-scaled
    sx8 qf[4][2];
    #pragma unroll
    for (int i = 0; i < 4; ++i) {
        const u16* qp = qb + bo + (w * 4 + i) * 65536 + (l0 + n16) * 64 + quad * 8;
        qf[i][0] = *(const sx8*)qp;
        qf[i][1] = *(const sx8*)(qp + 32);
    }

    fx4 of[4][4] = {};   // partial-O accumulators [head][d-tile]

    // ---- QK phase: S'^T(chunk t) -> S buffer (A-frag rows=m, B-frag cols=l) ----
    auto do_qk = [&](int t, u16* S) {
        const int m0 = mbase + t * MC;
        #pragma unroll
        for (int i = 0; i < 4; ++i) {
            const int h = w * 4 + i;
            const u16* kp = kt + bo + h * 65536 + (long)m0 * 64;
            #pragma unroll
            for (int nt = 0; nt < 4; ++nt) {
                const u16* kr = kp + (nt * 16 + n16) * 64 + quad * 8;
                fx4 s = {};
                s = MFMA(*(const sx8*)kr,        qf[i][0], s);
                s = MFMA(*(const sx8*)(kr + 32), qf[i][1], s);
                // D: row = m = quad*4 + reg (consecutive), col = l = n16
                // f2bf IR path (NOT asm): compiler inserts MFMA->VALU hazard waits
                uint2 pk;
                pk.x = (unsigned)f2bf(s[0]) | ((unsigned)f2bf(s[1]) << 16);
                pk.y = (unsigned)f2bf(s[2]) | ((unsigned)f2bf(s[3]) << 16);
                *(uint2*)&S[h * SH + n16 * LM + nt * 16 + quad * 4] = pk;
            }
        }
    };

    // ---- softmax over 16 heads, pointwise in (l,m); exp2 domain + max-sub ----
    auto do_softmax = [&](int t, u16* S) {
        const int m0 = mbase + t * MC;
        const int2 mk0 = *(const int2*)&mask[bo + (long)(l0 + sl0) * 1024 + m0 + smp0];
        const int2 mk1 = *(const int2*)&mask[bo + (long)(l0 + sl1) * 1024 + m0 + smp1];
        #pragma unroll
        for (int j = 0; j < 2; ++j) {
            const int l = j ? sl1 : sl0, mp = j ? smp1 : smp0;
            const int2 mk = j ? mk1 : mk0;
            u16* col = &S[l * LM + mp];
            float v0[16], v1[16], mx0 = -1e30f, mx1 = -1e30f;
            #pragma unroll
            for (int h = 0; h < 16; ++h) {
                unsigned pr = *(const unsigned*)&col[h * SH];
                float a = (mk.x == 0) ? MASKC : bf2f((u16)(pr & 0xffff));
                float b = (mk.y == 0) ? MASKC : bf2f((u16)(pr >> 16));
                v0[h] = a; v1[h] = b;
                mx0 = fmaxf(mx0, a); mx1 = fmaxf(mx1, b);
            }
            float s0 = 0.f, s1 = 0.f;
            #pragma unroll
            for (int h = 0; h < 16; ++h) {
                v0[h] = exp2f(v0[h] - mx0); s0 += v0[h];
                v1[h] = exp2f(v1[h] - mx1); s1 += v1[h];
            }
            const float i0 = __builtin_amdgcn_rcpf(s0);
            const float i1 = __builtin_amdgcn_rcpf(s1);
            #pragma unroll
            for (int h = 0; h < 16; ++h) {
                // cvt_pk on plain VALU inputs — R4/R8-proven pattern
                float e0 = v0[h] * i0, e1 = v1[h] * i1;
                unsigned pk_;
                asm("v_cvt_pk_bf16_f32 %0, %1, %2" : "=v"(pk_) : "v"(e0), "v"(e1));
                *(unsigned*)&col[h * SH] = pk_;
            }
        }
    };

    // ---- PV: of += P @ V (A-frag rows=l from S, B-frag from vt, m contiguous) ----
    auto do_pv = [&](int t, const u16* S) {
        const int m0 = mbase + t * MC;
        #pragma unroll
        for (int i = 0; i < 4; ++i) {
            const int h = w * 4 + i;
            const u16* sp = &S[h * SH + n16 * LM];
            sx8 a0 = *(const sx8*)(sp + quad * 8);
            sx8 a1 = *(const sx8*)(sp + 32 + quad * 8);
            const u16* vp = vt + bo + h * 65536 + (long)n16 * 1024 + m0 + quad * 8;
            #pragma unroll
            for (int dt = 0; dt < 4; ++dt) {
                of[i][dt] = MFMA(a0, *(const sx8*)(vp + dt * 16384),      of[i][dt]);
                of[i][dt] = MFMA(a1, *(const sx8*)(vp + dt * 16384 + 32), of[i][dt]);
            }
        }
    };

    // ---- pipelined main loop: 2 barriers/iter, QK hidden under softmax ----
    do_qk(0, Ss[0]);
    __syncthreads();
    for (int it = 0; it < 8; ++it) {
        const int cur = it & 1;
        if (it < 7) do_qk(it + 1, Ss[cur ^ 1]);   // matrix pipe
        do_softmax(it, Ss[cur]);                  // VALU pipe (independent buffer)
        __syncthreads();
        do_pv(it, Ss[cur]);
        __syncthreads();
    }

    // ---- epilogue: head-major flat store of this half's partial O ----
    #pragma unroll
    for (int i = 0; i < 4; ++i) {
        const int h = w * 4 + i;
        #pragma unroll
        for (int dt = 0; dt < 4; ++dt)
            #pragma unroll
            for (int r = 0; r < 4; ++r)
                po[bo + h * 65536 + (long)(l0 + quad * 4 + r) * 64 + dt * 16 + n16]
                    = f2bf(of[i][dt][r]);
    }
}

// ---------- bf16 partial-O reduction: b := bf16(a + b), element-wise in-place ----------
__global__ __launch_bounds__(256) void add_bf(
    const u16* __restrict__ a, u16* __restrict__ b)
{
    long i = ((long)blockIdx.x * 256 + threadIdx.x) * 8;
    uint4 x = *(const uint4*)(a + i);
    uint4 y = *(const uint4*)(b + i);
    uint4 r;
    unsigned* xp = (unsigned*)&x; unsigned* yp = (unsigned*)&y; unsigned* rp = (unsigned*)&r;
    #pragma unroll
    for (int k = 0; k < 4; ++k) {
        float lo = bf2f((u16)(xp[k] & 0xffff)) + bf2f((u16)(yp[k] & 0xffff));
        float hi = bf2f((u16)(xp[k] >> 16))    + bf2f((u16)(yp[k] >> 16));
        rp[k] = (unsigned)f2bf(lo) | ((unsigned)f2bf(hi) << 16);
    }
    *(uint4*)(b + i) = r;
}

// ---------- fp32 -> bf16 elementwise ----------
__global__ __launch_bounds__(256) void convert_f2b(
    const float* __restrict__ in, u16* __restrict__ out)
{
    long i = ((long)blockIdx.x * 256 + threadIdx.x) * 4;
    fx4 v = *(const fx4*)(in + i);
    uint2 o;
    o.x = (unsigned)f2bf(v[0]) | ((unsigned)f2bf(v[1]) << 16);
    o.y = (unsigned)f2bf(v[2]) | ((unsigned)f2bf(v[3]) << 16);
    *(uint2*)(out + i) = o;
}

// ---------- 4x fp32 [1024][1024] -> bf16 transposed, one launch (z selects src) ----------
__global__ __launch_bounds__(256) void transpose4_f2b(
    const float* a0, const float* a1, const float* a2, const float* a3,
    u16* __restrict__ out)
{
    __shared__ float t[32][33];
    const float* in = blockIdx.z == 0 ? a0 : blockIdx.z == 1 ? a1
                    : blockIdx.z == 2 ? a2 : a3;
    out += (long)blockIdx.z * 1048576;
    int c0 = blockIdx.x * 32, r0 = blockIdx.y * 32;
    int tx = threadIdx.x & 31, ty = threadIdx.x >> 5;
    #pragma unroll
    for (int i = 0; i < 4; ++i)
        t[ty + i * 8][tx] = in[(long)(r0 + ty + i * 8) * 1024 + c0 + tx];
    __syncthreads();
    #pragma unroll
    for (int i = 0; i < 4; ++i)
        out[(long)(c0 + ty + i * 8) * 1024 + r0 + tx] = f2bf(t[tx][ty + i * 8]);
}

// ---------- fp32 [R][C] -> bf16 transposed [C][R] ----------
__global__ __launch_bounds__(256) void transpose_f2b(
    const float* __restrict__ in, u16* __restrict__ out, int R, int C)
{
    __shared__ float t[32][33];
    int c0 = blockIdx.x * 32, r0 = blockIdx.y * 32;
    int tx = threadIdx.x & 31, ty = threadIdx.x >> 5;
    #pragma unroll
    for (int i = 0; i < 4; ++i)
        t[ty + i * 8][tx] = in[(long)(r0 + ty + i * 8) * C + c0 + tx];
    __syncthreads();
    #pragma unroll
    for (int i = 0; i < 4; ++i)
        out[(long)(c0 + ty + i * 8) * R + r0 + tx] = f2bf(t[tx][ty + i * 8]);
}

// ---------- bf16 batched transpose ----------
__global__ __launch_bounds__(256) void transpose_bf(
    const u16* __restrict__ in, u16* __restrict__ out, int R, int C)
{
    __shared__ u16 t[32][33];
    long zoff = (long)blockIdx.z * (long)R * (long)C;
    in += zoff; out += zoff;
    int c0 = blockIdx.x * 32, r0 = blockIdx.y * 32;
    int tx = threadIdx.x & 31, ty = threadIdx.x >> 5;
    #pragma unroll
    for (int i = 0; i < 4; ++i)
        t[ty + i * 8][tx] = in[(long)(r0 + ty + i * 8) * C + c0 + tx];
    __syncthreads();
    #pragma unroll
    for (int i = 0; i < 4; ++i)
        out[(long)(c0 + ty + i * 8) * R + r0 + tx] = t[tx][ty + i * 8];
}

// ---------- pack biases fp32 -> bf16 [bq|bk|bv|bc|b1|b2]; bq pre-scaled QSCALE ----------
__global__ __launch_bounds__(256) void pack_bias(
    const float* bq, const float* bk, const float* bv, const float* bc,
    const float* b1, const float* b2, u16* __restrict__ out)
{
    int i = blockIdx.x * 256 + threadIdx.x;
    float v;
    if      (i < 1024) v = bq[i] * QSCALE;
    else if (i < 2048) v = bk[i - 1024];
    else if (i < 3072) v = bv[i - 2048];
    else if (i < 4096) v = bc[i - 3072];
    else if (i < 8192) v = b1[i - 4096];
    else               v = b2[i - 8192];
    out[i] = f2bf(v);
}

// ---------- LayerNorm (ddof=1, /(std+eps)) ----------
__global__ __launch_bounds__(256) void layernorm_row(
    const u16* __restrict__ in, const float* __restrict__ g,
    const float* __restrict__ be, void* __restrict__ out, int outF32)
{
    int wave = threadIdx.x >> 6, lane = threadIdx.x & 63;
    long row = (long)blockIdx.x * 4 + wave;
    const u16* p = in + row * 1024 + lane * 16;

    float x[16];
    uint4 a = ((const uint4*)p)[0], b = ((const uint4*)p)[1];
    {
        unsigned u;
        u = a.x; x[0] = bf2f(u & 0xffff);  x[1] = bf2f(u >> 16);
        u = a.y; x[2] = bf2f(u & 0xffff);  x[3] = bf2f(u >> 16);
        u = a.z; x[4] = bf2f(u & 0xffff);  x[5] = bf2f(u >> 16);
        u = a.w; x[6] = bf2f(u & 0xffff);  x[7] = bf2f(u >> 16);
        u = b.x; x[8] = bf2f(u & 0xffff);  x[9] = bf2f(u >> 16);
        u = b.y; x[10] = bf2f(u & 0xffff); x[11] = bf2f(u >> 16);
        u = b.z; x[12] = bf2f(u & 0xffff); x[13] = bf2f(u >> 16);
        u = b.w; x[14] = bf2f(u & 0xffff); x[15] = bf2f(u >> 16);
    }
    float s = 0.f, ss = 0.f;
    #pragma unroll
    for (int i = 0; i < 16; ++i) { s += x[i]; ss += x[i] * x[i]; }
    #pragma unroll
    for (int o = 32; o >= 1; o >>= 1) { s += __shfl_down(s, o); ss += __shfl_down(ss, o); }
    s = __shfl(s, 0); ss = __shfl(ss, 0);
    float mean = s * (1.f / 1024.f);
    float var  = fmaxf((ss - 1024.f * mean * mean) * (1.f / 1023.f), 0.f);
    float rinv = 1.f / (sqrtf(var) + 1e-12f);

    int col = lane * 16;
    if (outF32) {
        float* ov = (float*)out + row * 1024 + col;
        #pragma unroll
        for (int i = 0; i < 16; ++i)
            ov[i] = g[col + i] * ((x[i] - mean) * rinv) + be[col + i];
    } else {
        u16* ov = (u16*)out + row * 1024 + col;
        #pragma unroll
        for (int i = 0; i < 16; ++i)
            ov[i] = f2bf(g[col + i] * ((x[i] - mean) * rinv) + be[col + i]);
    }
}

// ---------- launch ----------
// ws map (MB; peak 96 + 18KB bias):
//  [0,16)  xb -> p0 (m-half-0 partial O)
//  [16,22) wqkvT  [22,24) wcT (contiguous: one transpose4 launch)
//  [24,40) qb -> t0/x1
//  [40,56) kb -> vt (full V^T over dead kb) -> fh lower
//  [56,72) vb -> p1 (m-half-1 partial O) -> ao (after add_bf) -> fh upper
//  [72,88) kt (reshape-view K_t, all b) -> w1T/w2T post-attention
//  [88,96) pre2 (FFN phase; free during attention)
//  [96,+18KB) packed biases
extern "C" void kernel_launch(void* const* d_in, const int* in_sizes, int n_in,
                              void* d_out, int out_size, void* d_ws, size_t ws_size,
                              hipStream_t stream)
{
    const float* xf  = (const float*)d_in[0];
    const int* mask  = (const int*)d_in[1];
    const float* wq = (const float*)d_in[2];  const float* bq = (const float*)d_in[3];
    const float* wk = (const float*)d_in[4];  const float* bk = (const float*)d_in[5];
    const float* wv = (const float*)d_in[6];  const float* bv = (const float*)d_in[7];
    const float* wc = (const float*)d_in[8];  const float* bc = (const float*)d_in[9];
    const float* g1 = (const float*)d_in[10]; const float* be1 = (const float*)d_in[11];
    const float* w1 = (const float*)d_in[12]; const float* b1 = (const float*)d_in[13];
    const float* w2 = (const float*)d_in[14]; const float* b2 = (const float*)d_in[15];
    const float* g2 = (const float*)d_in[16]; const float* be2 = (const float*)d_in[17];

    char* ws = (char*)d_ws;
    const long MB = 1 << 20;
    u16* xb    = (u16*)(ws + 0 * MB);
    u16* wqkvT = (u16*)(ws + 16 * MB);
    u16* wcT   = (u16*)(ws + 22 * MB);
    u16* qb    = (u16*)(ws + 24 * MB);
    u16* kb    = (u16*)(ws + 40 * MB);
    u16* vb    = (u16*)(ws + 56 * MB);
    u16* kt    = (u16*)(ws + 72 * MB);
    u16* vt    = (u16*)(ws + 40 * MB);     // full V^T overlays dead kb
    u16* biasp = (u16*)(ws + 96 * MB);
    u16* p0   = xb;                        // m-half-0 partial O
    u16* p1   = vb;                        // m-half-1 partial O; becomes ao
    u16* ao   = p1;
    u16* t0   = qb;
    u16* fh   = kb;
    u16* w1T  = (u16*)(ws + 72 * MB);      // overlay kt post-attention
    u16* w2T  = (u16*)(ws + 80 * MB);
    u16* pre2 = (u16*)(ws + 88 * MB);

    dim3 blk(256);
    const long M1 = 1048576;

    // phase 0: conversions (wq|wk|wv|wc in ONE launch; dst contiguous)
    convert_f2b<<<dim3(8192), blk, 0, stream>>>(xf, xb);
    transpose4_f2b<<<dim3(32, 32, 4), blk, 0, stream>>>(wq, wk, wv, wc, wqkvT);
    pack_bias<<<dim3(36), blk, 0, stream>>>(bq, bk, bv, bc, b1, b2, biasp);

    // phase 1: fused QKV (Q projection pre-scaled by 0.125*log2e: z==0 only)
    gemm_bt<128><<<dim3(8, 64, 3), blk, 0, stream>>>(
        xb, 0, 1024, wqkvT, M1, 1024, qb, 8 * M1, 1024, 1024,
        biasp, 1024, nullptr, 0, 0, QSCALE, 1, 0);

    // phase 2: kt = reshape-view K_t transposed to [m][d], all (b,h)
    //          (must precede vt, which overwrites kb)
    transpose_bf<<<dim3(32, 2, 128), blk, 0, stream>>>(kb, kt, 64, 1024);

    // phase 3: full V^T, then 1024-block fused attention (XCD-swizzled, 4-wave)
    transpose_bf<<<dim3(2, 32, 128), blk, 0, stream>>>(vb, vt, 1024, 64);
    attn_fused<<<dim3(1024), blk, 0, stream>>>(qb, kt, vt, mask, p0, p1);
    // partial-O reduction: ao := p0 + p1 (in-place into p1)
    add_bf<<<dim3(4096), blk, 0, stream>>>(p0, p1);

    // phase 4: out-proj + bias + resid(x) -> t0 ; LN1 in-place
    gemm_bt<128><<<dim3(8, 64, 1), blk, 0, stream>>>(
        ao, 0, 1024, wcT, 0, 1024, t0, 0, 1024, 1024,
        biasp + 3072, 0, xf, 1, 0, 1.f, 0, 0);
    layernorm_row<<<dim3(2048), blk, 0, stream>>>(t0, g1, be1, t0, 0);

    // phase 5: FFN weight transposes into dead kt region
    transpose_f2b<<<dim3(128, 32), blk, 0, stream>>>(w1, w1T, 1024, 4096);
    transpose_f2b<<<dim3(32, 128), blk, 0, stream>>>(w2, w2T, 4096, 1024);

    // phase 6: FFN + LN2, 2 chunks of 4096 rows
    for (int c = 0; c < 2; ++c) {
        long r0 = (long)c * 4096 * 1024;
        gemm_bt<128><<<dim3(32, 32, 1), blk, 0, stream>>>(
            t0 + r0, 0, 1024, w1T, 0, 1024, fh, 0, 4096, 1024,
            biasp + 4096, 0, nullptr, 0, 0, 1.f, 0, 1);
        gemm_bt<64><<<dim3(16, 32, 1), blk, 0, stream>>>(
            fh, 0, 4096, w2T, 0, 4096, pre2, 0, 1024, 4096,
            biasp + 8192, 0, t0 + r0, 0, 0, 1.f, 0, 0);
        layernorm_row<<<dim3(1024), blk, 0, stream>>>(
            pre2, g2, be2, (float*)d_out + r0, 1);
    }
}

// Round 13
// 900.023 us; speedup vs baseline: 1.0802x; 1.0008x over previous
//
#include <hip/hip_runtime.h>
#include <stdint.h>

typedef unsigned short u16;
typedef __attribute__((ext_vector_type(8))) short sx8;   // 8 bf16 (4 VGPRs) — MFMA A/B frag
typedef __attribute__((ext_vector_type(4))) float fx4;   // MFMA C/D frag

__device__ __forceinline__ float bf2f(u16 u) {
    union { unsigned i; float f; } v; v.i = ((unsigned)u) << 16; return v.f;
}
__device__ __forceinline__ u16 f2bf(float f) {
    union { float f; unsigned i; } v; v.f = f;
    return (u16)((v.i + 0x7FFFu + ((v.i >> 16) & 1u)) >> 16);
}
#define MFMA(a, b, c) __builtin_amdgcn_mfma_f32_16x16x32_bf16((a), (b), (c), 0, 0, 0)

#define GLDS(gp, lp) \
    __builtin_amdgcn_global_load_lds((const __attribute__((address_space(1))) void*)(gp), \
                                     (__attribute__((address_space(3))) void*)(lp), 16, 0, 0)

// 0.125 (1/sqrt(64)) * log2(e): attention scale folded with the exp->exp2
// domain change. Softmax keeps max-subtraction (sum >= 1, NaN-proof);
// 2^(S'-mx)/sum equals natural-exp softmax exactly (base change cancels).
#define QSCALE 0.18033688011112042f
// masked score -1e-12 nats -> log2 domain
#define MASKC (-1.442695e-12f)

// ---------- m97-style MFMA GEMM: C[M,N] = A[M,K] @ BT[N,K]^T, all bf16 ----------
// Proven BK=32 form. scaleZ0: `scale` applies only to batch z==0 (folds the
// attention scale into the Q projection of the fused QKV GEMM).
template<int BN>
__global__ __launch_bounds__(256) void gemm_bt(
    const u16* __restrict__ A, long sA, int ldA,
    const u16* __restrict__ BT, long sBT, int ldBT,
    u16* __restrict__ C, long sC, int ldC,
    int K,
    const u16* __restrict__ bias, int bz,
    const void* __restrict__ resid, int residF32, long rofs,
    float scale, int scaleZ0, int relu)
{
    constexpr int BK = 32;
    constexpr int TM = 4;
    constexpr int TN = BN / 32;
    constexpr int AI = 2;
    constexpr int BI = BN / 64;

    __shared__ __align__(16) u16 As[128 * BK];
    __shared__ __align__(16) u16 Bs[BN * BK];

    const int tid  = threadIdx.x;
    const int w    = tid >> 6;
    const int lane = tid & 63;
    const int quad = lane >> 4;
    const int n16  = lane & 15;
    const int wrow = w >> 1, wcol = w & 1;

    // XCD-chunked swizzle over the (x,y) plane (bijective when nxy%8==0)
    int bx = blockIdx.x, by = blockIdx.y;
    {
        int nxy = gridDim.x * gridDim.y;
        if ((nxy & 7) == 0) {
            int bid = by * gridDim.x + bx;
            int wgs = (bid & 7) * (nxy >> 3) + (bid >> 3);
            bx = wgs % gridDim.x;
            by = wgs / gridDim.x;
        }
    }
    const int m0 = by * 128, n0 = bx * BN;
    const long z = blockIdx.z;
    const float es = (z == 0 || !scaleZ0) ? scale : 1.f;
    A  += z * sA;
    BT += z * sBT;
    C  += z * sC;

    fx4 acc[TM][TN] = {};

    for (int k0 = 0; k0 < K; k0 += BK) {
        #pragma unroll
        for (int i = 0; i < AI; ++i) {
            unsigned base = (unsigned)(w * AI + i) * 1024u;
            unsigned off  = base + (unsigned)lane * 16u;
            unsigned row  = off >> 6;
            unsigned col  = (off & 63u) >> 1;
            GLDS(A + (long)(m0 + row) * ldA + k0 + col, (char*)As + base);
        }
        #pragma unroll
        for (int i = 0; i < BI; ++i) {
            unsigned base = (unsigned)(w * BI + i) * 1024u;
            unsigned off  = base + (unsigned)lane * 16u;
            unsigned row  = off >> 6;
            unsigned col  = (off & 63u) >> 1;
            GLDS(BT + (long)(n0 + row) * ldBT + k0 + col, (char*)Bs + base);
        }
        __syncthreads();

        sx8 af[TM], bfr[TN];
        #pragma unroll
        for (int r = 0; r < TM; ++r)
            af[r] = *(const sx8*)&As[(wrow * 64 + r * 16 + n16) * BK + quad * 8];
        #pragma unroll
        for (int c = 0; c < TN; ++c)
            bfr[c] = *(const sx8*)&Bs[(wcol * (TN * 16) + c * 16 + n16) * BK + quad * 8];
        #pragma unroll
        for (int r = 0; r < TM; ++r)
            #pragma unroll
            for (int c = 0; c < TN; ++c)
                acc[r][c] = MFMA(af[r], bfr[c], acc[r][c]);
        __syncthreads();
    }

    #pragma unroll
    for (int r = 0; r < TM; ++r) {
        int row = m0 + wrow * 64 + r * 16 + quad * 4;
        #pragma unroll
        for (int c = 0; c < TN; ++c) {
            int col = n0 + wcol * (TN * 16) + c * 16 + n16;
            float bv = bias ? bf2f(bias[bz * (int)z + col]) : 0.f;
            #pragma unroll
            for (int g = 0; g < 4; ++g) {
                long idx = (long)(row + g) * ldC + col;
                float xv = acc[r][c][g] * es + bv;
                if (resid)
                    xv += residF32 ? ((const float*)resid)[rofs + idx]
                                   : bf2f(((const u16*)resid)[rofs + idx]);
                if (relu) xv = fmaxf(xv, 0.f);
                C[idx] = f2bf(xv);
            }
        }
    }
}

// ---------- fused attention: depth-3 phase-merged pipeline (R13) ----------
// R13 completes R12's merge: NO single-pipe region remains. Depth-3 software
// pipeline with triple-buffered S-tiles:
//   [ QK(t+2) || softmax(t+1) || PV(t) ] ; barrier      (one region/iter)
// Every region mixes matrix-pipe (QK+PV MFMAs) with VALU (softmax) so both
// pipes stay fed between barriers. MC halved to 32 so 3 buffers = 61.4 KB
// -> 2 blocks/CU retained (cross-wave fill preserved; R12 proved 2/CU is
// enough). Buffer rotation by pointer swap (no runtime-indexed reg arrays).
// Numerics identical to R12 (pure reorder; PV uses one K=32 MFMA per
// (head,dt) instead of two accumulating — same dot products).
// Frozen internals: exp2+max-sub softmax (NaN-proof), f2bf S-store
// (MFMA->asm-VALU hazard = R6/R7 NaN), cvt_pk P-store on plain-VALU inputs,
// rcpf, mask prefetch, XCD-chunked swizzle, in-sequence chunk order (R10:
// rotation thrashes L2), 2-way m-split + add_bf reduction.
// qb [b][16h][1024 l][64 d]; kt [(b,h)][m][d] reshape-view K_t; vt [b][16h][64 d][1024 m].
__global__ __launch_bounds__(256, 2) void attn_fused(
    const u16* __restrict__ qb, const u16* __restrict__ kt,
    const u16* __restrict__ vt, const int* __restrict__ mask,
    u16* __restrict__ p0, u16* __restrict__ p1)
{
    constexpr int MC = 32;           // m-chunk (halved for triple-buffer)
    constexpr int LM = MC + 8;       // 40 u16 = 80 B (rows stay 16B-aligned)
    constexpr int SH = 16 * LM;      // per-head stride = 640 u16
    constexpr int NB = 16 * SH;      // one buffer = 10240 u16 = 20,480 B
    __shared__ __align__(16) u16 Ss[3 * NB];   // 61,440 B -> 2 blocks/CU

    const int tid = threadIdx.x, w = tid >> 6, lane = tid & 63;
    const int quad = lane >> 4, n16 = lane & 15;

    // XCD-chunked swizzle (1024 blocks, 8 XCDs, bijective)
    const int wg = ((blockIdx.x & 7) << 7) + (blockIdx.x >> 3);
    const int l0 = (wg & 63) * 16;
    const long bo = (long)((wg >> 6) & 7) * 1048576;
    const int zz = wg >> 9;
    const int mbase = zz * 512;
    u16* __restrict__ po = zz ? p1 : p0;

    // softmax work split: 16 l x 16 m-pairs = 256 positions, 1 per thread
    const int sl = tid >> 4, smp = (tid & 15) * 2;

    // resident Q B-frags for this wave's 4 heads (col=l, k=d); Q pre-scaled
    sx8 qf[4][2];
    #pragma unroll
    for (int i = 0; i < 4; ++i) {
        const u16* qp = qb + bo + (w * 4 + i) * 65536 + (l0 + n16) * 64 + quad * 8;
        qf[i][0] = *(const sx8*)qp;
        qf[i][1] = *(const sx8*)(qp + 32);
    }

    fx4 of[4][4] = {};   // partial-O accumulators [head][d-tile]

    // ---- QK: S'^T(chunk t, 32 m) -> S buffer (A-frag rows=m, B-frag cols=l) ----
    auto do_qk = [&](int t, u16* S) {
        const int m0 = mbase + t * MC;
        #pragma unroll
        for (int i = 0; i < 4; ++i) {
            const int h = w * 4 + i;
            const u16* kp = kt + bo + h * 65536 + (long)m0 * 64;
            #pragma unroll
            for (int nt = 0; nt < 2; ++nt) {
                const u16* kr = kp + (nt * 16 + n16) * 64 + quad * 8;
                fx4 s = {};
                s = MFMA(*(const sx8*)kr,        qf[i][0], s);
                s = MFMA(*(const sx8*)(kr + 32), qf[i][1], s);
                // D: row = m = quad*4 + reg (consecutive), col = l = n16
                // f2bf IR path (NOT asm): compiler inserts MFMA->VALU hazard waits
                uint2 pk;
                pk.x = (unsigned)f2bf(s[0]) | ((unsigned)f2bf(s[1]) << 16);
                pk.y = (unsigned)f2bf(s[2]) | ((unsigned)f2bf(s[3]) << 16);
                *(uint2*)&S[h * SH + n16 * LM + nt * 16 + quad * 4] = pk;
            }
        }
    };

    // ---- softmax over 16 heads, pointwise in (l,m); exp2 domain + max-sub ----
    auto do_softmax = [&](int t, u16* S) {
        const int m0 = mbase + t * MC;
        const int2 mk = *(const int2*)&mask[bo + (long)(l0 + sl) * 1024 + m0 + smp];
        u16* col = &S[sl * LM + smp];
        float v0[16], v1[16], mx0 = -1e30f, mx1 = -1e30f;
        #pragma unroll
        for (int h = 0; h < 16; ++h) {
            unsigned pr = *(const unsigned*)&col[h * SH];
            float a = (mk.x == 0) ? MASKC : bf2f((u16)(pr & 0xffff));
            float b = (mk.y == 0) ? MASKC : bf2f((u16)(pr >> 16));
            v0[h] = a; v1[h] = b;
            mx0 = fmaxf(mx0, a); mx1 = fmaxf(mx1, b);
        }
        float s0 = 0.f, s1 = 0.f;
        #pragma unroll
        for (int h = 0; h < 16; ++h) {
            v0[h] = exp2f(v0[h] - mx0); s0 += v0[h];
            v1[h] = exp2f(v1[h] - mx1); s1 += v1[h];
        }
        const float i0 = __builtin_amdgcn_rcpf(s0);
        const float i1 = __builtin_amdgcn_rcpf(s1);
        #pragma unroll
        for (int h = 0; h < 16; ++h) {
            // cvt_pk on plain VALU inputs — R4/R8-proven pattern
            float e0 = v0[h] * i0, e1 = v1[h] * i1;
            unsigned pk_;
            asm("v_cvt_pk_bf16_f32 %0, %1, %2" : "=v"(pk_) : "v"(e0), "v"(e1));
            *(unsigned*)&col[h * SH] = pk_;
        }
    };

    // ---- PV: of += P @ V over this 32-m chunk (one K=32 MFMA per head,dt) ----
    auto do_pv = [&](int t, const u16* S) {
        const int m0 = mbase + t * MC;
        #pragma unroll
        for (int i = 0; i < 4; ++i) {
            const int h = w * 4 + i;
            sx8 af = *(const sx8*)&S[h * SH + n16 * LM + quad * 8];
            const u16* vp = vt + bo + h * 65536 + (long)n16 * 1024 + m0 + quad * 8;
            #pragma unroll
            for (int dt = 0; dt < 4; ++dt)
                of[i][dt] = MFMA(af, *(const sx8*)(vp + dt * 16384), of[i][dt]);
        }
    };

    // ---- depth-3 pipeline: every region mixes QK || softmax || PV ----
    u16* bA = Ss;                // will hold P(t) for PV
    u16* bB = Ss + NB;           // will hold S(t+1) for softmax
    u16* bC = Ss + 2 * NB;       // QK(t+2) destination
    do_qk(0, bA);
    __syncthreads();
    do_qk(1, bB);
    do_softmax(0, bA);
    __syncthreads();
    for (int t = 0; t < 16; ++t) {
        if (t + 2 < 16) do_qk(t + 2, bC);      // matrix pipe
        if (t + 1 < 16) do_softmax(t + 1, bB); // VALU pipe
        do_pv(t, bA);                          // matrix pipe
        __syncthreads();
        u16* tmp = bA; bA = bB; bB = bC; bC = tmp;
    }

    // ---- epilogue: head-major flat store of this half's partial O ----
    #pragma unroll
    for (int i = 0; i < 4; ++i) {
        const int h = w * 4 + i;
        #pragma unroll
        for (int dt = 0; dt < 4; ++dt)
            #pragma unroll
            for (int r = 0; r < 4; ++r)
                po[bo + h * 65536 + (long)(l0 + quad * 4 + r) * 64 + dt * 16 + n16]
                    = f2bf(of[i][dt][r]);
    }
}

// ---------- bf16 partial-O reduction: b := bf16(a + b), element-wise in-place ----------
__global__ __launch_bounds__(256) void add_bf(
    const u16* __restrict__ a, u16* __restrict__ b)
{
    long i = ((long)blockIdx.x * 256 + threadIdx.x) * 8;
    uint4 x = *(const uint4*)(a + i);
    uint4 y = *(const uint4*)(b + i);
    uint4 r;
    unsigned* xp = (unsigned*)&x; unsigned* yp = (unsigned*)&y; unsigned* rp = (unsigned*)&r;
    #pragma unroll
    for (int k = 0; k < 4; ++k) {
        float lo = bf2f((u16)(xp[k] & 0xffff)) + bf2f((u16)(yp[k] & 0xffff));
        float hi = bf2f((u16)(xp[k] >> 16))    + bf2f((u16)(yp[k] >> 16));
        rp[k] = (unsigned)f2bf(lo) | ((unsigned)f2bf(hi) << 16);
    }
    *(uint4*)(b + i) = r;
}

// ---------- fp32 -> bf16 elementwise ----------
__global__ __launch_bounds__(256) void convert_f2b(
    const float* __restrict__ in, u16* __restrict__ out)
{
    long i = ((long)blockIdx.x * 256 + threadIdx.x) * 4;
    fx4 v = *(const fx4*)(in + i);
    uint2 o;
    o.x = (unsigned)f2bf(v[0]) | ((unsigned)f2bf(v[1]) << 16);
    o.y = (unsigned)f2bf(v[2]) | ((unsigned)f2bf(v[3]) << 16);
    *(uint2*)(out + i) = o;
}

// ---------- 4x fp32 [1024][1024] -> bf16 transposed, one launch (z selects src) ----------
__global__ __launch_bounds__(256) void transpose4_f2b(
    const float* a0, const float* a1, const float* a2, const float* a3,
    u16* __restrict__ out)
{
    __shared__ float t[32][33];
    const float* in = blockIdx.z == 0 ? a0 : blockIdx.z == 1 ? a1
                    : blockIdx.z == 2 ? a2 : a3;
    out += (long)blockIdx.z * 1048576;
    int c0 = blockIdx.x * 32, r0 = blockIdx.y * 32;
    int tx = threadIdx.x & 31, ty = threadIdx.x >> 5;
    #pragma unroll
    for (int i = 0; i < 4; ++i)
        t[ty + i * 8][tx] = in[(long)(r0 + ty + i * 8) * 1024 + c0 + tx];
    __syncthreads();
    #pragma unroll
    for (int i = 0; i < 4; ++i)
        out[(long)(c0 + ty + i * 8) * 1024 + r0 + tx] = f2bf(t[tx][ty + i * 8]);
}

// ---------- fp32 [R][C] -> bf16 transposed [C][R] ----------
__global__ __launch_bounds__(256) void transpose_f2b(
    const float* __restrict__ in, u16* __restrict__ out, int R, int C)
{
    __shared__ float t[32][33];
    int c0 = blockIdx.x * 32, r0 = blockIdx.y * 32;
    int tx = threadIdx.x & 31, ty = threadIdx.x >> 5;
    #pragma unroll
    for (int i = 0; i < 4; ++i)
        t[ty + i * 8][tx] = in[(long)(r0 + ty + i * 8) * C + c0 + tx];
    __syncthreads();
    #pragma unroll
    for (int i = 0; i < 4; ++i)
        out[(long)(c0 + ty + i * 8) * R + r0 + tx] = f2bf(t[tx][ty + i * 8]);
}

// ---------- bf16 batched transpose ----------
__global__ __launch_bounds__(256) void transpose_bf(
    const u16* __restrict__ in, u16* __restrict__ out, int R, int C)
{
    __shared__ u16 t[32][33];
    long zoff = (long)blockIdx.z * (long)R * (long)C;
    in += zoff; out += zoff;
    int c0 = blockIdx.x * 32, r0 = blockIdx.y * 32;
    int tx = threadIdx.x & 31, ty = threadIdx.x >> 5;
    #pragma unroll
    for (int i = 0; i < 4; ++i)
        t[ty + i * 8][tx] = in[(long)(r0 + ty + i * 8) * C + c0 + tx];
    __syncthreads();
    #pragma unroll
    for (int i = 0; i < 4; ++i)
        out[(long)(c0 + ty + i * 8) * R + r0 + tx] = t[tx][ty + i * 8];
}

// ---------- pack biases fp32 -> bf16 [bq|bk|bv|bc|b1|b2]; bq pre-scaled QSCALE ----------
__global__ __launch_bounds__(256) void pack_bias(
    const float* bq, const float* bk, const float* bv, const float* bc,
    const float* b1, const float* b2, u16* __restrict__ out)
{
    int i = blockIdx.x * 256 + threadIdx.x;
    float v;
    if      (i < 1024) v = bq[i] * QSCALE;
    else if (i < 2048) v = bk[i - 1024];
    else if (i < 3072) v = bv[i - 2048];
    else if (i < 4096) v = bc[i - 3072];
    else if (i < 8192) v = b1[i - 4096];
    else               v = b2[i - 8192];
    out[i] = f2bf(v);
}

// ---------- LayerNorm (ddof=1, /(std+eps)) ----------
__global__ __launch_bounds__(256) void layernorm_row(
    const u16* __restrict__ in, const float* __restrict__ g,
    const float* __restrict__ be, void* __restrict__ out, int outF32)
{
    int wave = threadIdx.x >> 6, lane = threadIdx.x & 63;
    long row = (long)blockIdx.x * 4 + wave;
    const u16* p = in + row * 1024 + lane * 16;

    float x[16];
    uint4 a = ((const uint4*)p)[0], b = ((const uint4*)p)[1];
    {
        unsigned u;
        u = a.x; x[0] = bf2f(u & 0xffff);  x[1] = bf2f(u >> 16);
        u = a.y; x[2] = bf2f(u & 0xffff);  x[3] = bf2f(u >> 16);
        u = a.z; x[4] = bf2f(u & 0xffff);  x[5] = bf2f(u >> 16);
        u = a.w; x[6] = bf2f(u & 0xffff);  x[7] = bf2f(u >> 16);
        u = b.x; x[8] = bf2f(u & 0xffff);  x[9] = bf2f(u >> 16);
        u = b.y; x[10] = bf2f(u & 0xffff); x[11] = bf2f(u >> 16);
        u = b.z; x[12] = bf2f(u & 0xffff); x[13] = bf2f(u >> 16);
        u = b.w; x[14] = bf2f(u & 0xffff); x[15] = bf2f(u >> 16);
    }
    float s = 0.f, ss = 0.f;
    #pragma unroll
    for (int i = 0; i < 16; ++i) { s += x[i]; ss += x[i] * x[i]; }
    #pragma unroll
    for (int o = 32; o >= 1; o >>= 1) { s += __shfl_down(s, o); ss += __shfl_down(ss, o); }
    s = __shfl(s, 0); ss = __shfl(ss, 0);
    float mean = s * (1.f / 1024.f);
    float var  = fmaxf((ss - 1024.f * mean * mean) * (1.f / 1023.f), 0.f);
    float rinv = 1.f / (sqrtf(var) + 1e-12f);

    int col = lane * 16;
    if (outF32) {
        float* ov = (float*)out + row * 1024 + col;
        #pragma unroll
        for (int i = 0; i < 16; ++i)
            ov[i] = g[col + i] * ((x[i] - mean) * rinv) + be[col + i];
    } else {
        u16* ov = (u16*)out + row * 1024 + col;
        #pragma unroll
        for (int i = 0; i < 16; ++i)
            ov[i] = f2bf(g[col + i] * ((x[i] - mean) * rinv) + be[col + i]);
    }
}

// ---------- launch ----------
// ws map (MB; peak 96 + 18KB bias):
//  [0,16)  xb -> p0 (m-half-0 partial O)
//  [16,22) wqkvT  [22,24) wcT (contiguous: one transpose4 launch)
//  [24,40) qb -> t0/x1
//  [40,56) kb -> vt (full V^T over dead kb) -> fh lower
//  [56,72) vb -> p1 (m-half-1 partial O) -> ao (after add_bf) -> fh upper
//  [72,88) kt (reshape-view K_t, all b) -> w1T/w2T post-attention
//  [88,96) pre2 (FFN phase; free during attention)
//  [96,+18KB) packed biases
extern "C" void kernel_launch(void* const* d_in, const int* in_sizes, int n_in,
                              void* d_out, int out_size, void* d_ws, size_t ws_size,
                              hipStream_t stream)
{
    const float* xf  = (const float*)d_in[0];
    const int* mask  = (const int*)d_in[1];
    const float* wq = (const float*)d_in[2];  const float* bq = (const float*)d_in[3];
    const float* wk = (const float*)d_in[4];  const float* bk = (const float*)d_in[5];
    const float* wv = (const float*)d_in[6];  const float* bv = (const float*)d_in[7];
    const float* wc = (const float*)d_in[8];  const float* bc = (const float*)d_in[9];
    const float* g1 = (const float*)d_in[10]; const float* be1 = (const float*)d_in[11];
    const float* w1 = (const float*)d_in[12]; const float* b1 = (const float*)d_in[13];
    const float* w2 = (const float*)d_in[14]; const float* b2 = (const float*)d_in[15];
    const float* g2 = (const float*)d_in[16]; const float* be2 = (const float*)d_in[17];

    char* ws = (char*)d_ws;
    const long MB = 1 << 20;
    u16* xb    = (u16*)(ws + 0 * MB);
    u16* wqkvT = (u16*)(ws + 16 * MB);
    u16* wcT   = (u16*)(ws + 22 * MB);
    u16* qb    = (u16*)(ws + 24 * MB);
    u16* kb    = (u16*)(ws + 40 * MB);
    u16* vb    = (u16*)(ws + 56 * MB);
    u16* kt    = (u16*)(ws + 72 * MB);
    u16* vt    = (u16*)(ws + 40 * MB);     // full V^T overlays dead kb
    u16* biasp = (u16*)(ws + 96 * MB);
    u16* p0   = xb;                        // m-half-0 partial O
    u16* p1   = vb;                        // m-half-1 partial O; becomes ao
    u16* ao   = p1;
    u16* t0   = qb;
    u16* fh   = kb;
    u16* w1T  = (u16*)(ws + 72 * MB);      // overlay kt post-attention
    u16* w2T  = (u16*)(ws + 80 * MB);
    u16* pre2 = (u16*)(ws + 88 * MB);

    dim3 blk(256);
    const long M1 = 1048576;

    // phase 0: conversions (wq|wk|wv|wc in ONE launch; dst contiguous)
    convert_f2b<<<dim3(8192), blk, 0, stream>>>(xf, xb);
    transpose4_f2b<<<dim3(32, 32, 4), blk, 0, stream>>>(wq, wk, wv, wc, wqkvT);
    pack_bias<<<dim3(36), blk, 0, stream>>>(bq, bk, bv, bc, b1, b2, biasp);

    // phase 1: fused QKV (Q projection pre-scaled by 0.125*log2e: z==0 only)
    gemm_bt<128><<<dim3(8, 64, 3), blk, 0, stream>>>(
        xb, 0, 1024, wqkvT, M1, 1024, qb, 8 * M1, 1024, 1024,
        biasp, 1024, nullptr, 0, 0, QSCALE, 1, 0);

    // phase 2: kt = reshape-view K_t transposed to [m][d], all (b,h)
    //          (must precede vt, which overwrites kb)
    transpose_bf<<<dim3(32, 2, 128), blk, 0, stream>>>(kb, kt, 64, 1024);

    // phase 3: full V^T, then 1024-block fused attention (XCD-swizzled, 4-wave)
    transpose_bf<<<dim3(2, 32, 128), blk, 0, stream>>>(vb, vt, 1024, 64);
    attn_fused<<<dim3(1024), blk, 0, stream>>>(qb, kt, vt, mask, p0, p1);
    // partial-O reduction: ao := p0 + p1 (in-place into p1)
    add_bf<<<dim3(4096), blk, 0, stream>>>(p0, p1);

    // phase 4: out-proj + bias + resid(x) -> t0 ; LN1 in-place
    gemm_bt<128><<<dim3(8, 64, 1), blk, 0, stream>>>(
        ao, 0, 1024, wcT, 0, 1024, t0, 0, 1024, 1024,
        biasp + 3072, 0, xf, 1, 0, 1.f, 0, 0);
    layernorm_row<<<dim3(2048), blk, 0, stream>>>(t0, g1, be1, t0, 0);

    // phase 5: FFN weight transposes into dead kt region
    transpose_f2b<<<dim3(128, 32), blk, 0, stream>>>(w1, w1T, 1024, 4096);
    transpose_f2b<<<dim3(32, 128), blk, 0, stream>>>(w2, w2T, 4096, 1024);

    // phase 6: FFN + LN2, 2 chunks of 4096 rows
    for (int c = 0; c < 2; ++c) {
        long r0 = (long)c * 4096 * 1024;
        gemm_bt<128><<<dim3(32, 32, 1), blk, 0, stream>>>(
            t0 + r0, 0, 1024, w1T, 0, 1024, fh, 0, 4096, 1024,
            biasp + 4096, 0, nullptr, 0, 0, 1.f, 0, 1);
        gemm_bt<64><<<dim3(16, 32, 1), blk, 0, stream>>>(
            fh, 0, 4096, w2T, 0, 4096, pre2, 0, 1024, 4096,
            biasp + 8192, 0, t0 + r0, 0, 0, 1.f, 0, 0);
        layernorm_row<<<dim3(1024), blk, 0, stream>>>(
            pre2, g2, be2, (float*)d_out + r0, 1);
    }
}

// Round 14
// 881.465 us; speedup vs baseline: 1.1030x; 1.0211x over previous
//
#include <hip/hip_runtime.h>
#include <stdint.h>

typedef unsigned short u16;
typedef __attribute__((ext_vector_type(8))) short sx8;   // 8 bf16 (4 VGPRs) — MFMA A/B frag
typedef __attribute__((ext_vector_type(4))) float fx4;   // MFMA C/D frag

__device__ __forceinline__ float bf2f(u16 u) {
    union { unsigned i; float f; } v; v.i = ((unsigned)u) << 16; return v.f;
}
__device__ __forceinline__ u16 f2bf(float f) {
    union { float f; unsigned i; } v; v.f = f;
    return (u16)((v.i + 0x7FFFu + ((v.i >> 16) & 1u)) >> 16);
}
#define MFMA(a, b, c) __builtin_amdgcn_mfma_f32_16x16x32_bf16((a), (b), (c), 0, 0, 0)

#define GLDS(gp, lp) \
    __builtin_amdgcn_global_load_lds((const __attribute__((address_space(1))) void*)(gp), \
                                     (__attribute__((address_space(3))) void*)(lp), 16, 0, 0)

// 0.125 (1/sqrt(64)) * log2(e): attention scale folded with the exp->exp2
// domain change. Softmax keeps max-subtraction (sum >= 1, NaN-proof);
// 2^(S'-mx)/sum equals natural-exp softmax exactly (base change cancels).
#define QSCALE 0.18033688011112042f
// masked score -1e-12 nats -> log2 domain
#define MASKC (-1.442695e-12f)

// ---------- m97-style MFMA GEMM: C[M,N] = A[M,K] @ BT[N,K]^T, all bf16 ----------
// Proven BK=32 form. scaleZ0: `scale` applies only to batch z==0 (folds the
// attention scale into the Q projection of the fused QKV GEMM).
template<int BN>
__global__ __launch_bounds__(256) void gemm_bt(
    const u16* __restrict__ A, long sA, int ldA,
    const u16* __restrict__ BT, long sBT, int ldBT,
    u16* __restrict__ C, long sC, int ldC,
    int K,
    const u16* __restrict__ bias, int bz,
    const void* __restrict__ resid, int residF32, long rofs,
    float scale, int scaleZ0, int relu)
{
    constexpr int BK = 32;
    constexpr int TM = 4;
    constexpr int TN = BN / 32;
    constexpr int AI = 2;
    constexpr int BI = BN / 64;

    __shared__ __align__(16) u16 As[128 * BK];
    __shared__ __align__(16) u16 Bs[BN * BK];

    const int tid  = threadIdx.x;
    const int w    = tid >> 6;
    const int lane = tid & 63;
    const int quad = lane >> 4;
    const int n16  = lane & 15;
    const int wrow = w >> 1, wcol = w & 1;

    // XCD-chunked swizzle over the (x,y) plane (bijective when nxy%8==0)
    int bx = blockIdx.x, by = blockIdx.y;
    {
        int nxy = gridDim.x * gridDim.y;
        if ((nxy & 7) == 0) {
            int bid = by * gridDim.x + bx;
            int wgs = (bid & 7) * (nxy >> 3) + (bid >> 3);
            bx = wgs % gridDim.x;
            by = wgs / gridDim.x;
        }
    }
    const int m0 = by * 128, n0 = bx * BN;
    const long z = blockIdx.z;
    const float es = (z == 0 || !scaleZ0) ? scale : 1.f;
    A  += z * sA;
    BT += z * sBT;
    C  += z * sC;

    fx4 acc[TM][TN] = {};

    for (int k0 = 0; k0 < K; k0 += BK) {
        #pragma unroll
        for (int i = 0; i < AI; ++i) {
            unsigned base = (unsigned)(w * AI + i) * 1024u;
            unsigned off  = base + (unsigned)lane * 16u;
            unsigned row  = off >> 6;
            unsigned col  = (off & 63u) >> 1;
            GLDS(A + (long)(m0 + row) * ldA + k0 + col, (char*)As + base);
        }
        #pragma unroll
        for (int i = 0; i < BI; ++i) {
            unsigned base = (unsigned)(w * BI + i) * 1024u;
            unsigned off  = base + (unsigned)lane * 16u;
            unsigned row  = off >> 6;
            unsigned col  = (off & 63u) >> 1;
            GLDS(BT + (long)(n0 + row) * ldBT + k0 + col, (char*)Bs + base);
        }
        __syncthreads();

        sx8 af[TM], bfr[TN];
        #pragma unroll
        for (int r = 0; r < TM; ++r)
            af[r] = *(const sx8*)&As[(wrow * 64 + r * 16 + n16) * BK + quad * 8];
        #pragma unroll
        for (int c = 0; c < TN; ++c)
            bfr[c] = *(const sx8*)&Bs[(wcol * (TN * 16) + c * 16 + n16) * BK + quad * 8];
        #pragma unroll
        for (int r = 0; r < TM; ++r)
            #pragma unroll
            for (int c = 0; c < TN; ++c)
                acc[r][c] = MFMA(af[r], bfr[c], acc[r][c]);
        __syncthreads();
    }

    #pragma unroll
    for (int r = 0; r < TM; ++r) {
        int row = m0 + wrow * 64 + r * 16 + quad * 4;
        #pragma unroll
        for (int c = 0; c < TN; ++c) {
            int col = n0 + wcol * (TN * 16) + c * 16 + n16;
            float bv = bias ? bf2f(bias[bz * (int)z + col]) : 0.f;
            #pragma unroll
            for (int g = 0; g < 4; ++g) {
                long idx = (long)(row + g) * ldC + col;
                float xv = acc[r][c][g] * es + bv;
                if (resid)
                    xv += residF32 ? ((const float*)resid)[rofs + idx]
                                   : bf2f(((const u16*)resid)[rofs + idx]);
                if (relu) xv = fmaxf(xv, 0.f);
                C[idx] = f2bf(xv);
            }
        }
    }
}

// ---------- fused attention: depth-2 phase-merged pipeline, full m-span (R14) ----------
// R14 = R12's proven depth-2 merge (attn 264us; R13's depth-3/MC=32 regressed
// to 276 — reverted) with the 2-way m-split DELETED: at 2 blocks/CU a
// 512-block grid is already fully resident, so the split only cost an extra
// add_bf pass + partial-O round trip + a bf16 double-rounding. Each block now
// walks all 16 m-chunks of its (l-tile, b); O accumulates in fp32 throughout.
//   QK(0); bar;  for t in 0..15: { [QK(t+1) || softmax(t)]; bar; PV(t); bar }
// XCD property preserved: 512 blocks, each XCD = 64 consecutive wg = all 64
// l-tiles of ONE batch, streaming the same K/V chunk in lockstep (R10-proven
// L2 sharing; in-sequence chunk order REQUIRED).
// Frozen internals: exp2+max-sub softmax (NaN-proof), f2bf S-store
// (MFMA->asm-VALU hazard = R6/R7 NaN), cvt_pk P-store on plain-VALU inputs,
// rcpf, mask prefetch, double-buffered Ss (73.7KB -> 2 blocks/CU).
// qb [b][16h][1024 l][64 d]; kt [(b,h)][m][d] reshape-view K_t; vt [b][16h][64 d][1024 m].
__global__ __launch_bounds__(256, 2) void attn_fused(
    const u16* __restrict__ qb, const u16* __restrict__ kt,
    const u16* __restrict__ vt, const int* __restrict__ mask,
    u16* __restrict__ ao)
{
    constexpr int MC = 64;           // m-chunk
    constexpr int LM = MC + 8;       // 72 (pad; rows stay 16B-aligned: 144B stride)
    constexpr int SH = 16 * LM;      // per-head stride = 1152 u16
    __shared__ __align__(16) u16 Ss[2][16 * SH];   // 2 x 36,864 B = 73,728 B

    const int tid = threadIdx.x, w = tid >> 6, lane = tid & 63;
    const int quad = lane >> 4, n16 = lane & 15;

    // XCD-chunked swizzle (512 blocks, 8 XCDs, bijective): XCD k owns batch k
    const int wg = ((blockIdx.x & 7) << 6) + (blockIdx.x >> 3);
    const int l0 = (wg & 63) * 16;
    const long bo = (long)(wg >> 6) * 1048576;

    // softmax work split: thread covers (l, m-pair) p = tid + 256*j
    const int sl0 = tid >> 5,         smp0 = (tid & 31) * 2;
    const int sl1 = (tid + 256) >> 5, smp1 = ((tid + 256) & 31) * 2;

    // resident Q B-frags for this wave's 4 heads (col=l, k=d); Q pre-scaled
    sx8 qf[4][2];
    #pragma unroll
    for (int i = 0; i < 4; ++i) {
        const u16* qp = qb + bo + (w * 4 + i) * 65536 + (l0 + n16) * 64 + quad * 8;
        qf[i][0] = *(const sx8*)qp;
        qf[i][1] = *(const sx8*)(qp + 32);
    }

    fx4 of[4][4] = {};   // O accumulators [head][d-tile], fp32 across all m

    // ---- QK phase: S'^T(chunk t) -> S buffer (A-frag rows=m, B-frag cols=l) ----
    auto do_qk = [&](int t, u16* S) {
        const int m0 = t * MC;
        #pragma unroll
        for (int i = 0; i < 4; ++i) {
            const int h = w * 4 + i;
            const u16* kp = kt + bo + h * 65536 + (long)m0 * 64;
            #pragma unroll
            for (int nt = 0; nt < 4; ++nt) {
                const u16* kr = kp + (nt * 16 + n16) * 64 + quad * 8;
                fx4 s = {};
                s = MFMA(*(const sx8*)kr,        qf[i][0], s);
                s = MFMA(*(const sx8*)(kr + 32), qf[i][1], s);
                // D: row = m = quad*4 + reg (consecutive), col = l = n16
                // f2bf IR path (NOT asm): compiler inserts MFMA->VALU hazard waits
                uint2 pk;
                pk.x = (unsigned)f2bf(s[0]) | ((unsigned)f2bf(s[1]) << 16);
                pk.y = (unsigned)f2bf(s[2]) | ((unsigned)f2bf(s[3]) << 16);
                *(uint2*)&S[h * SH + n16 * LM + nt * 16 + quad * 4] = pk;
            }
        }
    };

    // ---- softmax over 16 heads, pointwise in (l,m); exp2 domain + max-sub ----
    auto do_softmax = [&](int t, u16* S) {
        const int m0 = t * MC;
        const int2 mk0 = *(const int2*)&mask[bo + (long)(l0 + sl0) * 1024 + m0 + smp0];
        const int2 mk1 = *(const int2*)&mask[bo + (long)(l0 + sl1) * 1024 + m0 + smp1];
        #pragma unroll
        for (int j = 0; j < 2; ++j) {
            const int l = j ? sl1 : sl0, mp = j ? smp1 : smp0;
            const int2 mk = j ? mk1 : mk0;
            u16* col = &S[l * LM + mp];
            float v0[16], v1[16], mx0 = -1e30f, mx1 = -1e30f;
            #pragma unroll
            for (int h = 0; h < 16; ++h) {
                unsigned pr = *(const unsigned*)&col[h * SH];
                float a = (mk.x == 0) ? MASKC : bf2f((u16)(pr & 0xffff));
                float b = (mk.y == 0) ? MASKC : bf2f((u16)(pr >> 16));
                v0[h] = a; v1[h] = b;
                mx0 = fmaxf(mx0, a); mx1 = fmaxf(mx1, b);
            }
            float s0 = 0.f, s1 = 0.f;
            #pragma unroll
            for (int h = 0; h < 16; ++h) {
                v0[h] = exp2f(v0[h] - mx0); s0 += v0[h];
                v1[h] = exp2f(v1[h] - mx1); s1 += v1[h];
            }
            const float i0 = __builtin_amdgcn_rcpf(s0);
            const float i1 = __builtin_amdgcn_rcpf(s1);
            #pragma unroll
            for (int h = 0; h < 16; ++h) {
                // cvt_pk on plain VALU inputs — R4/R8-proven pattern
                float e0 = v0[h] * i0, e1 = v1[h] * i1;
                unsigned pk_;
                asm("v_cvt_pk_bf16_f32 %0, %1, %2" : "=v"(pk_) : "v"(e0), "v"(e1));
                *(unsigned*)&col[h * SH] = pk_;
            }
        }
    };

    // ---- PV: of += P @ V (A-frag rows=l from S, B-frag from vt, m contiguous) ----
    auto do_pv = [&](int t, const u16* S) {
        const int m0 = t * MC;
        #pragma unroll
        for (int i = 0; i < 4; ++i) {
            const int h = w * 4 + i;
            const u16* sp = &S[h * SH + n16 * LM];
            sx8 a0 = *(const sx8*)(sp + quad * 8);
            sx8 a1 = *(const sx8*)(sp + 32 + quad * 8);
            const u16* vp = vt + bo + h * 65536 + (long)n16 * 1024 + m0 + quad * 8;
            #pragma unroll
            for (int dt = 0; dt < 4; ++dt) {
                of[i][dt] = MFMA(a0, *(const sx8*)(vp + dt * 16384),      of[i][dt]);
                of[i][dt] = MFMA(a1, *(const sx8*)(vp + dt * 16384 + 32), of[i][dt]);
            }
        }
    };

    // ---- pipelined main loop: 2 barriers/iter, QK hidden under softmax ----
    do_qk(0, Ss[0]);
    __syncthreads();
    for (int it = 0; it < 16; ++it) {
        const int cur = it & 1;
        if (it < 15) do_qk(it + 1, Ss[cur ^ 1]);  // matrix pipe
        do_softmax(it, Ss[cur]);                  // VALU pipe (independent buffer)
        __syncthreads();
        do_pv(it, Ss[cur]);
        __syncthreads();
    }

    // ---- epilogue: head-major flat store of full O ----
    #pragma unroll
    for (int i = 0; i < 4; ++i) {
        const int h = w * 4 + i;
        #pragma unroll
        for (int dt = 0; dt < 4; ++dt)
            #pragma unroll
            for (int r = 0; r < 4; ++r)
                ao[bo + h * 65536 + (long)(l0 + quad * 4 + r) * 64 + dt * 16 + n16]
                    = f2bf(of[i][dt][r]);
    }
}

// ---------- fp32 -> bf16 elementwise ----------
__global__ __launch_bounds__(256) void convert_f2b(
    const float* __restrict__ in, u16* __restrict__ out)
{
    long i = ((long)blockIdx.x * 256 + threadIdx.x) * 4;
    fx4 v = *(const fx4*)(in + i);
    uint2 o;
    o.x = (unsigned)f2bf(v[0]) | ((unsigned)f2bf(v[1]) << 16);
    o.y = (unsigned)f2bf(v[2]) | ((unsigned)f2bf(v[3]) << 16);
    *(uint2*)(out + i) = o;
}

// ---------- 4x fp32 [1024][1024] -> bf16 transposed, one launch (z selects src) ----------
__global__ __launch_bounds__(256) void transpose4_f2b(
    const float* a0, const float* a1, const float* a2, const float* a3,
    u16* __restrict__ out)
{
    __shared__ float t[32][33];
    const float* in = blockIdx.z == 0 ? a0 : blockIdx.z == 1 ? a1
                    : blockIdx.z == 2 ? a2 : a3;
    out += (long)blockIdx.z * 1048576;
    int c0 = blockIdx.x * 32, r0 = blockIdx.y * 32;
    int tx = threadIdx.x & 31, ty = threadIdx.x >> 5;
    #pragma unroll
    for (int i = 0; i < 4; ++i)
        t[ty + i * 8][tx] = in[(long)(r0 + ty + i * 8) * 1024 + c0 + tx];
    __syncthreads();
    #pragma unroll
    for (int i = 0; i < 4; ++i)
        out[(long)(c0 + ty + i * 8) * 1024 + r0 + tx] = f2bf(t[tx][ty + i * 8]);
}

// ---------- fp32 [R][C] -> bf16 transposed [C][R] ----------
__global__ __launch_bounds__(256) void transpose_f2b(
    const float* __restrict__ in, u16* __restrict__ out, int R, int C)
{
    __shared__ float t[32][33];
    int c0 = blockIdx.x * 32, r0 = blockIdx.y * 32;
    int tx = threadIdx.x & 31, ty = threadIdx.x >> 5;
    #pragma unroll
    for (int i = 0; i < 4; ++i)
        t[ty + i * 8][tx] = in[(long)(r0 + ty + i * 8) * C + c0 + tx];
    __syncthreads();
    #pragma unroll
    for (int i = 0; i < 4; ++i)
        out[(long)(c0 + ty + i * 8) * R + r0 + tx] = f2bf(t[tx][ty + i * 8]);
}

// ---------- bf16 batched transpose ----------
__global__ __launch_bounds__(256) void transpose_bf(
    const u16* __restrict__ in, u16* __restrict__ out, int R, int C)
{
    __shared__ u16 t[32][33];
    long zoff = (long)blockIdx.z * (long)R * (long)C;
    in += zoff; out += zoff;
    int c0 = blockIdx.x * 32, r0 = blockIdx.y * 32;
    int tx = threadIdx.x & 31, ty = threadIdx.x >> 5;
    #pragma unroll
    for (int i = 0; i < 4; ++i)
        t[ty + i * 8][tx] = in[(long)(r0 + ty + i * 8) * C + c0 + tx];
    __syncthreads();
    #pragma unroll
    for (int i = 0; i < 4; ++i)
        out[(long)(c0 + ty + i * 8) * R + r0 + tx] = t[tx][ty + i * 8];
}

// ---------- pack biases fp32 -> bf16 [bq|bk|bv|bc|b1|b2]; bq pre-scaled QSCALE ----------
__global__ __launch_bounds__(256) void pack_bias(
    const float* bq, const float* bk, const float* bv, const float* bc,
    const float* b1, const float* b2, u16* __restrict__ out)
{
    int i = blockIdx.x * 256 + threadIdx.x;
    float v;
    if      (i < 1024) v = bq[i] * QSCALE;
    else if (i < 2048) v = bk[i - 1024];
    else if (i < 3072) v = bv[i - 2048];
    else if (i < 4096) v = bc[i - 3072];
    else if (i < 8192) v = b1[i - 4096];
    else               v = b2[i - 8192];
    out[i] = f2bf(v);
}

// ---------- LayerNorm (ddof=1, /(std+eps)) ----------
__global__ __launch_bounds__(256) void layernorm_row(
    const u16* __restrict__ in, const float* __restrict__ g,
    const float* __restrict__ be, void* __restrict__ out, int outF32)
{
    int wave = threadIdx.x >> 6, lane = threadIdx.x & 63;
    long row = (long)blockIdx.x * 4 + wave;
    const u16* p = in + row * 1024 + lane * 16;

    float x[16];
    uint4 a = ((const uint4*)p)[0], b = ((const uint4*)p)[1];
    {
        unsigned u;
        u = a.x; x[0] = bf2f(u & 0xffff);  x[1] = bf2f(u >> 16);
        u = a.y; x[2] = bf2f(u & 0xffff);  x[3] = bf2f(u >> 16);
        u = a.z; x[4] = bf2f(u & 0xffff);  x[5] = bf2f(u >> 16);
        u = a.w; x[6] = bf2f(u & 0xffff);  x[7] = bf2f(u >> 16);
        u = b.x; x[8] = bf2f(u & 0xffff);  x[9] = bf2f(u >> 16);
        u = b.y; x[10] = bf2f(u & 0xffff); x[11] = bf2f(u >> 16);
        u = b.z; x[12] = bf2f(u & 0xffff); x[13] = bf2f(u >> 16);
        u = b.w; x[14] = bf2f(u & 0xffff); x[15] = bf2f(u >> 16);
    }
    float s = 0.f, ss = 0.f;
    #pragma unroll
    for (int i = 0; i < 16; ++i) { s += x[i]; ss += x[i] * x[i]; }
    #pragma unroll
    for (int o = 32; o >= 1; o >>= 1) { s += __shfl_down(s, o); ss += __shfl_down(ss, o); }
    s = __shfl(s, 0); ss = __shfl(ss, 0);
    float mean = s * (1.f / 1024.f);
    float var  = fmaxf((ss - 1024.f * mean * mean) * (1.f / 1023.f), 0.f);
    float rinv = 1.f / (sqrtf(var) + 1e-12f);

    int col = lane * 16;
    if (outF32) {
        float* ov = (float*)out + row * 1024 + col;
        #pragma unroll
        for (int i = 0; i < 16; ++i)
            ov[i] = g[col + i] * ((x[i] - mean) * rinv) + be[col + i];
    } else {
        u16* ov = (u16*)out + row * 1024 + col;
        #pragma unroll
        for (int i = 0; i < 16; ++i)
            ov[i] = f2bf(g[col + i] * ((x[i] - mean) * rinv) + be[col + i]);
    }
}

// ---------- launch ----------
// ws map (MB; peak 96 + 18KB bias):
//  [0,16)  xb (dead after QKV)
//  [16,22) wqkvT  [22,24) wcT (contiguous: one transpose4 launch)
//  [24,40) qb -> t0/x1
//  [40,56) kb -> vt (full V^T over dead kb) -> fh lower
//  [56,72) vb -> ao (attn out over dead vb) -> fh upper
//  [72,88) kt (reshape-view K_t, all b) -> w1T/w2T post-attention
//  [88,96) pre2 (FFN phase; free during attention)
//  [96,+18KB) packed biases
extern "C" void kernel_launch(void* const* d_in, const int* in_sizes, int n_in,
                              void* d_out, int out_size, void* d_ws, size_t ws_size,
                              hipStream_t stream)
{
    const float* xf  = (const float*)d_in[0];
    const int* mask  = (const int*)d_in[1];
    const float* wq = (const float*)d_in[2];  const float* bq = (const float*)d_in[3];
    const float* wk = (const float*)d_in[4];  const float* bk = (const float*)d_in[5];
    const float* wv = (const float*)d_in[6];  const float* bv = (const float*)d_in[7];
    const float* wc = (const float*)d_in[8];  const float* bc = (const float*)d_in[9];
    const float* g1 = (const float*)d_in[10]; const float* be1 = (const float*)d_in[11];
    const float* w1 = (const float*)d_in[12]; const float* b1 = (const float*)d_in[13];
    const float* w2 = (const float*)d_in[14]; const float* b2 = (const float*)d_in[15];
    const float* g2 = (const float*)d_in[16]; const float* be2 = (const float*)d_in[17];

    char* ws = (char*)d_ws;
    const long MB = 1 << 20;
    u16* xb    = (u16*)(ws + 0 * MB);
    u16* wqkvT = (u16*)(ws + 16 * MB);
    u16* wcT   = (u16*)(ws + 22 * MB);
    u16* qb    = (u16*)(ws + 24 * MB);
    u16* kb    = (u16*)(ws + 40 * MB);
    u16* vb    = (u16*)(ws + 56 * MB);
    u16* kt    = (u16*)(ws + 72 * MB);
    u16* vt    = (u16*)(ws + 40 * MB);     // full V^T overlays dead kb
    u16* biasp = (u16*)(ws + 96 * MB);
    u16* ao   = vb;                        // attn out overlays dead vb
    u16* t0   = qb;
    u16* fh   = kb;
    u16* w1T  = (u16*)(ws + 72 * MB);      // overlay kt post-attention
    u16* w2T  = (u16*)(ws + 80 * MB);
    u16* pre2 = (u16*)(ws + 88 * MB);

    dim3 blk(256);
    const long M1 = 1048576;

    // phase 0: conversions (wq|wk|wv|wc in ONE launch; dst contiguous)
    convert_f2b<<<dim3(8192), blk, 0, stream>>>(xf, xb);
    transpose4_f2b<<<dim3(32, 32, 4), blk, 0, stream>>>(wq, wk, wv, wc, wqkvT);
    pack_bias<<<dim3(36), blk, 0, stream>>>(bq, bk, bv, bc, b1, b2, biasp);

    // phase 1: fused QKV (Q projection pre-scaled by 0.125*log2e: z==0 only)
    gemm_bt<128><<<dim3(8, 64, 3), blk, 0, stream>>>(
        xb, 0, 1024, wqkvT, M1, 1024, qb, 8 * M1, 1024, 1024,
        biasp, 1024, nullptr, 0, 0, QSCALE, 1, 0);

    // phase 2: kt = reshape-view K_t transposed to [m][d], all (b,h)
    //          (must precede vt, which overwrites kb)
    transpose_bf<<<dim3(32, 2, 128), blk, 0, stream>>>(kb, kt, 64, 1024);

    // phase 3: full V^T, then 512-block fused attention (XCD-swizzled, depth-2
    //          pipeline, full m-span — no partial-O reduction needed)
    transpose_bf<<<dim3(2, 32, 128), blk, 0, stream>>>(vb, vt, 1024, 64);
    attn_fused<<<dim3(512), blk, 0, stream>>>(qb, kt, vt, mask, ao);

    // phase 4: out-proj + bias + resid(x) -> t0 ; LN1 in-place
    gemm_bt<128><<<dim3(8, 64, 1), blk, 0, stream>>>(
        ao, 0, 1024, wcT, 0, 1024, t0, 0, 1024, 1024,
        biasp + 3072, 0, xf, 1, 0, 1.f, 0, 0);
    layernorm_row<<<dim3(2048), blk, 0, stream>>>(t0, g1, be1, t0, 0);

    // phase 5: FFN weight transposes into dead kt region
    transpose_f2b<<<dim3(128, 32), blk, 0, stream>>>(w1, w1T, 1024, 4096);
    transpose_f2b<<<dim3(32, 128), blk, 0, stream>>>(w2, w2T, 4096, 1024);

    // phase 6: FFN + LN2, 2 chunks of 4096 rows
    for (int c = 0; c < 2; ++c) {
        long r0 = (long)c * 4096 * 1024;
        gemm_bt<128><<<dim3(32, 32, 1), blk, 0, stream>>>(
            t0 + r0, 0, 1024, w1T, 0, 1024, fh, 0, 4096, 1024,
            biasp + 4096, 0, nullptr, 0, 0, 1.f, 0, 1);
        gemm_bt<64><<<dim3(16, 32, 1), blk, 0, stream>>>(
            fh, 0, 4096, w2T, 0, 4096, pre2, 0, 1024, 4096,
            biasp + 8192, 0, t0 + r0, 0, 0, 1.f, 0, 0);
        layernorm_row<<<dim3(1024), blk, 0, stream>>>(
            pre2, g2, be2, (float*)d_out + r0, 1);
    }
}